// Round 4
// baseline (232.727 us; speedup 1.0000x reference)
//
#include <hip/hip_runtime.h>
#include <hip/hip_bf16.h>

#define N_NODES 50000
#define N_EDGES 800000
#define D 64
#define B 64
#define HL 128
#define OUT 32

#define CAP 64          // max in-degree capacity (Poisson(16): P(>=64) ~ 1e-18)
#define STP 72          // LDS transform tile row stride (ushorts)
#define ZROW N_NODES    // sentinel index (u16-safe: 50000 < 65536)

#define BINS 196        // ceil(N_NODES/256): coarse bins of 256 nodes (dst>>8)
#define EPB 8192        // edges per block in binA
#define LCAP 76         // per-(block,bin) LDS staging cap (mean 41.8, +5.3 sigma)
#define BCAP 4608       // per-bin global region cap (mean 4082)

#define AB 98           // binA blocks (98*8192 >= 800000)
#define MB 782          // mlp blocks (64 nodes each)

typedef __attribute__((ext_vector_type(8))) short          short8;
typedef __attribute__((ext_vector_type(8))) unsigned short ushort8_t;
typedef __attribute__((ext_vector_type(4))) float          floatx4;

// bf16 helpers (RNE pack, cheap unpack)
__device__ __forceinline__ unsigned short f2bf(float f)
{
    unsigned u = __float_as_uint(f);
    u = (u + 0x7FFFu + ((u >> 16) & 1u)) >> 16;
    return (unsigned short)u;
}
__device__ __forceinline__ float bfLO(unsigned u) { return __uint_as_float(u << 16); }
__device__ __forceinline__ float bfHI(unsigned u) { return __uint_as_float(u & 0xffff0000u); }

// ---------------------------------------------------------------------------
// Prologue, block-range roles:
//   [0, AB)      : binA — bin edges by dst>>8 via LDS staging (8192 edges/blk)
//   [AB, AB+4)   : weight cvt — w1..w4 -> bf16 (one matrix per block)
//   AB+4         : init — h1 sentinel row, psum/cnts zero
// bincnt is zeroed by a prior 1KB memset.
// ---------------------------------------------------------------------------
__global__ __launch_bounds__(256) void pro_kernel(
    const int*   __restrict__ ei,
    int*         __restrict__ bincnt,
    unsigned*    __restrict__ binbuf,
    const float* __restrict__ w1, const float* __restrict__ w2,
    const float* __restrict__ w3, const float* __restrict__ w4,
    unsigned short* __restrict__ wb,
    unsigned short* __restrict__ h1,
    float*       __restrict__ psum,
    float*       __restrict__ cnts)
{
    __shared__ int      lcnt[BINS];
    __shared__ int      gbase[BINS];
    __shared__ unsigned lbuf[BINS * LCAP];   // 59.6 KB

    int t = threadIdx.x;

    if (blockIdx.x < AB) {
        // ---------------- binA ----------------
        if (t < BINS) lcnt[t] = 0;
        __syncthreads();

        int base = blockIdx.x * EPB;
#pragma unroll 8
        for (int i = 0; i < EPB / 256; ++i) {
            int e = base + i * 256 + t;
            if (e < N_EDGES) {
                int s = ei[e];
                int d = ei[N_EDGES + e];
                int bin = d >> 8;
                unsigned pk = (unsigned)s | ((unsigned)(d & 255) << 16);
                int p = atomicAdd(&lcnt[bin], 1);
                if (p < LCAP) {
                    lbuf[bin * LCAP + p] = pk;
                } else {                          // statistically never
                    int q = atomicAdd(&bincnt[bin], 1);
                    if (q < BCAP) binbuf[bin * BCAP + q] = pk;
                }
            }
        }
        __syncthreads();

        if (t < BINS) {
            int m = lcnt[t]; m = (m < LCAP) ? m : LCAP;
            gbase[t] = (m > 0) ? atomicAdd(&bincnt[t], m) : 0;
        }
        __syncthreads();

        int wv = t >> 6, lane = t & 63;
        for (int b = wv; b < BINS; b += 4) {
            int m = lcnt[b]; m = (m < LCAP) ? m : LCAP;
            int gb = gbase[b];
            for (int j = lane; j < m; j += 64)
                if (gb + j < BCAP) binbuf[b * BCAP + gb + j] = lbuf[b * LCAP + j];
        }
    } else if (blockIdx.x < AB + 4) {
        // ---------------- weight cvt ----------------
        int m = blockIdx.x - AB;
        const float* src = (m == 0) ? w1 : (m == 1) ? w2 : (m == 2) ? w3 : w4;
#pragma unroll
        for (int k = 0; k < 16; ++k) {
            int off = k * 256 + t;               // 4096 elems
            wb[m * 4096 + off] = f2bf(src[off]);
        }
    } else {
        // ---------------- init ----------------
        if (t < D) h1[(size_t)ZROW * D + t] = 0; // sentinel zero row (bf16)
#pragma unroll
        for (int k = 0; k < 16; ++k)             // psum[B*64] = 0
            psum[t * 16 + k] = 0.0f;
        if (t < B) cnts[t] = 0.0f;
    }
}

// ---------------------------------------------------------------------------
// Per-block LDS bucket build: the block's 64 nodes are one quarter of one
// 256-node bin. Scan the bin's packed-edge region, keep entries whose dlow
// falls in our quarter. Rows pre-filled with ZROW -> branchless gather.
// Must be called by ALL 256 threads (contains __syncthreads).
// ---------------------------------------------------------------------------
__device__ __forceinline__ void build_bucket64(
    const int*      __restrict__ bincnt,
    const unsigned* __restrict__ binbuf,
    unsigned short* lbkt,     // [64*CAP + 16] LDS
    int*            lc,       // [64] LDS
    int bn0, int t)
{
    {
        ushort8_t fill = {ZROW, ZROW, ZROW, ZROW, ZROW, ZROW, ZROW, ZROW};
        reinterpret_cast<ushort8_t*>(lbkt)[t]       = fill;
        reinterpret_cast<ushort8_t*>(lbkt)[t + 256] = fill;
    }
    if (t < 64) lc[t] = 0;
    __syncthreads();

    const int bin = bn0 >> 8;
    const int q   = (bn0 >> 6) & 3;              // quarter within the bin
    int m = bincnt[bin]; m = (m < BCAP) ? m : BCAP;
    const unsigned* src = binbuf + bin * BCAP;
    for (int j = t; j < m; j += 256) {
        unsigned pk = src[j];
        int dlow = (pk >> 16) & 255;
        if ((dlow >> 6) == q) {
            int r = dlow & 63;
            int p = atomicAdd(&lc[r], 1);
            if (p < CAP) lbkt[r * CAP + p] = (unsigned short)(pk & 0xFFFFu);
        }
    }
    __syncthreads();
}

// ---------------------------------------------------------------------------
// Gather (fp32 source): wave's 16-node tile -> LDS transform tile (bf16).
// Wave processes 4 nodes at a time: group g = lane>>4 owns node
// bn0+wv*16+b*4+g; lane c = lane&15 owns dims 4c..4c+3 (float4 = 16 B/lane).
// Padded bucket entries (ZROW) are clamped to row 0 and masked via fma.
// ---------------------------------------------------------------------------
__device__ __forceinline__ void gather16_f32(
    const float*          __restrict__ x,
    const unsigned short* lbkt,          // [64*CAP] LDS (+pad)
    const int*            lc,            // [64] LDS
    unsigned short*       stw,           // wave's LDS tile, 16 rows x STP
    int bn0, int wv, int lane)
{
    const int g = lane >> 4;
    const int c = lane & 15;

#pragma unroll
    for (int b = 0; b < 4; ++b) {
        const int rloc = wv * 16 + b * 4 + g;
        const int node = bn0 + rloc;
        int deg = lc[rloc];
        deg = (deg < CAP) ? deg : CAP;
        int m = (deg + 7) >> 3;
        {   // wave-max over the 4 groups
            int t1 = __shfl_xor(m, 16); m = (t1 > m) ? t1 : m;
            int t2 = __shfl_xor(m, 32); m = (t2 > m) ? t2 : m;
        }

        const unsigned short* bkt = lbkt + rloc * CAP;

        // self row
        float4 u = *reinterpret_cast<const float4*>(x + (size_t)node * D + 4 * c);
        float a0 = u.x, a1 = u.y, a2 = u.z, a3 = u.w;

        ushort8_t idx = *reinterpret_cast<const ushort8_t*>(bkt);
        for (int r = 0; r < m; ++r) {
            ushort8_t nxt = *reinterpret_cast<const ushort8_t*>(bkt + (r + 1) * 8);
#pragma unroll
            for (int j = 0; j < 8; ++j) {
                int id = idx[j];
                float msk = (id < N_NODES) ? 1.0f : 0.0f;
                int id2   = (id < N_NODES) ? id : 0;
                float4 v = *reinterpret_cast<const float4*>(
                    x + (size_t)id2 * D + 4 * c);
                a0 = fmaf(v.x, msk, a0);
                a1 = fmaf(v.y, msk, a1);
                a2 = fmaf(v.z, msk, a2);
                a3 = fmaf(v.w, msk, a3);
            }
            idx = nxt;
        }

        uint2 o;
        o.x = (unsigned)f2bf(a0) | ((unsigned)f2bf(a1) << 16);
        o.y = (unsigned)f2bf(a2) | ((unsigned)f2bf(a3) << 16);
        *reinterpret_cast<uint2*>(stw + (b * 4 + g) * STP + 4 * c) = o;
    }
}

// ---------------------------------------------------------------------------
// Gather (bf16 source, ZROW-sentinel row valid): as above with uint2 loads.
// ---------------------------------------------------------------------------
__device__ __forceinline__ void gather16_bf16(
    const unsigned short* __restrict__ feat,
    const unsigned short* lbkt,
    const int*            lc,
    unsigned short*       stw,
    int bn0, int wv, int lane)
{
    const int g = lane >> 4;
    const int c = lane & 15;

#pragma unroll
    for (int b = 0; b < 4; ++b) {
        const int rloc = wv * 16 + b * 4 + g;
        const int node = bn0 + rloc;
        int deg = lc[rloc];
        deg = (deg < CAP) ? deg : CAP;
        int m = (deg + 7) >> 3;
        {
            int t1 = __shfl_xor(m, 16); m = (t1 > m) ? t1 : m;
            int t2 = __shfl_xor(m, 32); m = (t2 > m) ? t2 : m;
        }

        const unsigned short* bkt = lbkt + rloc * CAP;

        uint2 u = *reinterpret_cast<const uint2*>(feat + (size_t)node * D + 4 * c);
        float a0 = bfLO(u.x), a1 = bfHI(u.x);
        float a2 = bfLO(u.y), a3 = bfHI(u.y);

        ushort8_t idx = *reinterpret_cast<const ushort8_t*>(bkt);
        for (int r = 0; r < m; ++r) {
            ushort8_t nxt = *reinterpret_cast<const ushort8_t*>(bkt + (r + 1) * 8);
#pragma unroll
            for (int j = 0; j < 8; ++j) {
                uint2 v = *reinterpret_cast<const uint2*>(
                    feat + (size_t)idx[j] * D + 4 * c);
                a0 += bfLO(v.x); a1 += bfHI(v.x);
                a2 += bfLO(v.y); a3 += bfHI(v.y);
            }
            idx = nxt;
        }

        uint2 o;
        o.x = (unsigned)f2bf(a0) | ((unsigned)f2bf(a1) << 16);
        o.y = (unsigned)f2bf(a2) | ((unsigned)f2bf(a3) << 16);
        *reinterpret_cast<uint2*>(stw + (b * 4 + g) * STP + 4 * c) = o;
    }
}

// ---------------------------------------------------------------------------
// Fused bucket-build + fp32-gather + MLP layer 1 via MFMA (m89/m91 layouts).
// ---------------------------------------------------------------------------
__global__ __launch_bounds__(256) void gmlp_kernel(
    const float*          __restrict__ x,      // fp32 node features
    const int*            __restrict__ bincnt,
    const unsigned*       __restrict__ binbuf,
    const unsigned short* __restrict__ wAb,
    const float*          __restrict__ bA,
    const unsigned short* __restrict__ wBb,
    const float*          __restrict__ bB,
    unsigned short*       __restrict__ outp)
{
    __shared__ int lc[64];
    __shared__ __align__(16) unsigned short lbkt[64 * CAP + 16];  // 8.2 KB
    __shared__ __align__(16) unsigned short st[4][16 * STP];      // 9.2 KB

    const int t    = threadIdx.x;
    const int wv   = t >> 6;
    const int lane = t & 63;
    const int quad = lane >> 4;
    const int col  = lane & 15;

    const int bn0 = blockIdx.x * 64;
    const int n0  = bn0 + wv * 16;

    build_bucket64(bincnt, binbuf, lbkt, lc, bn0, t);

    if (n0 >= N_NODES) return;                   // after barriers: safe

    float bAl[4], bBl[4];
#pragma unroll
    for (int tt = 0; tt < 4; ++tt) {
        bAl[tt] = bA[tt * 16 + col];
        bBl[tt] = bB[tt * 16 + col];
    }

    short8 WA[4][2], WB[4][2];
#pragma unroll
    for (int tt = 0; tt < 4; ++tt)
#pragma unroll
        for (int k = 0; k < 2; ++k) {
            WA[tt][k] = *reinterpret_cast<const short8*>(
                wAb + (tt * 16 + col) * D + k * 32 + quad * 8);
            WB[tt][k] = *reinterpret_cast<const short8*>(
                wBb + (tt * 16 + col) * D + k * 32 + quad * 8);
        }

    unsigned short* stw = &st[wv][0];

    gather16_f32(x, lbkt, lc, stw, bn0, wv, lane);

    short8 A0 = *reinterpret_cast<const short8*>(stw + col * STP + 0 * 32 + quad * 8);
    short8 A1 = *reinterpret_cast<const short8*>(stw + col * STP + 1 * 32 + quad * 8);

#pragma unroll
    for (int tt = 0; tt < 4; ++tt) {
        floatx4 c = {0.0f, 0.0f, 0.0f, 0.0f};
        c = __builtin_amdgcn_mfma_f32_16x16x32_bf16(A0, WA[tt][0], c, 0, 0, 0);
        c = __builtin_amdgcn_mfma_f32_16x16x32_bf16(A1, WA[tt][1], c, 0, 0, 0);
#pragma unroll
        for (int r = 0; r < 4; ++r) {
            float v = fmaxf(c[r] + bAl[tt], 0.0f);
            stw[(quad * 4 + r) * STP + tt * 16 + col] = f2bf(v);
        }
    }

    short8 T0 = *reinterpret_cast<const short8*>(stw + col * STP + 0 * 32 + quad * 8);
    short8 T1 = *reinterpret_cast<const short8*>(stw + col * STP + 1 * 32 + quad * 8);

#pragma unroll
    for (int tt = 0; tt < 4; ++tt) {
        floatx4 c = {0.0f, 0.0f, 0.0f, 0.0f};
        c = __builtin_amdgcn_mfma_f32_16x16x32_bf16(T0, WB[tt][0], c, 0, 0, 0);
        c = __builtin_amdgcn_mfma_f32_16x16x32_bf16(T1, WB[tt][1], c, 0, 0, 0);
#pragma unroll
        for (int r = 0; r < 4; ++r) {
            float v = fmaxf(c[r] + bBl[tt], 0.0f);
            outp[(size_t)(n0 + quad * 4 + r) * D + tt * 16 + col] = f2bf(v);
        }
    }
}

// ---------------------------------------------------------------------------
// Fused bucket-build + bf16-gather + MLP layer 2 + mean-pool numerator +
// per-graph node counts (for the head's mean).
// ---------------------------------------------------------------------------
__global__ __launch_bounds__(256) void g2mlp_pool_kernel(
    const unsigned short* __restrict__ feat,   // h1 (layer-1 output, bf16)
    const int*            __restrict__ bincnt,
    const unsigned*       __restrict__ binbuf,
    const unsigned short* __restrict__ wAb,
    const float*          __restrict__ bA,
    const unsigned short* __restrict__ wBb,
    const float*          __restrict__ bB,
    const int*            __restrict__ batch,  // [N] sorted
    float*                __restrict__ psum,   // [B,64] zero-initialized
    float*                __restrict__ cnts)   // [B] zero-initialized
{
    __shared__ int lc[64];
    __shared__ __align__(16) unsigned short lbkt[64 * CAP + 16];
    __shared__ __align__(16) unsigned short st[4][16 * STP];
    __shared__ float pt[64][D + 1];            // block's 64-node output tile
    __shared__ int   sbatch[64];

    const int t    = threadIdx.x;
    const int wv   = t >> 6;
    const int lane = t & 63;
    const int quad = lane >> 4;
    const int col  = lane & 15;

    const int bn0 = blockIdx.x * 64;
    const int n0  = bn0 + wv * 16;
    const bool active = (n0 < N_NODES);

    if (t < 64) {
        int n = bn0 + t;
        sbatch[t] = (n < N_NODES) ? batch[n] : -1;
    }
    // (sbatch covered by build_bucket64's first __syncthreads)

    build_bucket64(bincnt, binbuf, lbkt, lc, bn0, t);

    if (active) {
        float bAl[4], bBl[4];
#pragma unroll
        for (int tt = 0; tt < 4; ++tt) {
            bAl[tt] = bA[tt * 16 + col];
            bBl[tt] = bB[tt * 16 + col];
        }

        short8 WA[4][2], WB[4][2];
#pragma unroll
        for (int tt = 0; tt < 4; ++tt)
#pragma unroll
            for (int k = 0; k < 2; ++k) {
                WA[tt][k] = *reinterpret_cast<const short8*>(
                    wAb + (tt * 16 + col) * D + k * 32 + quad * 8);
                WB[tt][k] = *reinterpret_cast<const short8*>(
                    wBb + (tt * 16 + col) * D + k * 32 + quad * 8);
            }

        unsigned short* stw = &st[wv][0];

        gather16_bf16(feat, lbkt, lc, stw, bn0, wv, lane);

        short8 A0 = *reinterpret_cast<const short8*>(stw + col * STP + 0 * 32 + quad * 8);
        short8 A1 = *reinterpret_cast<const short8*>(stw + col * STP + 1 * 32 + quad * 8);

#pragma unroll
        for (int tt = 0; tt < 4; ++tt) {
            floatx4 c = {0.0f, 0.0f, 0.0f, 0.0f};
            c = __builtin_amdgcn_mfma_f32_16x16x32_bf16(A0, WA[tt][0], c, 0, 0, 0);
            c = __builtin_amdgcn_mfma_f32_16x16x32_bf16(A1, WA[tt][1], c, 0, 0, 0);
#pragma unroll
            for (int r = 0; r < 4; ++r) {
                float v = fmaxf(c[r] + bAl[tt], 0.0f);
                stw[(quad * 4 + r) * STP + tt * 16 + col] = f2bf(v);
            }
        }

        short8 T0 = *reinterpret_cast<const short8*>(stw + col * STP + 0 * 32 + quad * 8);
        short8 T1 = *reinterpret_cast<const short8*>(stw + col * STP + 1 * 32 + quad * 8);

#pragma unroll
        for (int tt = 0; tt < 4; ++tt) {
            floatx4 c = {0.0f, 0.0f, 0.0f, 0.0f};
            c = __builtin_amdgcn_mfma_f32_16x16x32_bf16(T0, WB[tt][0], c, 0, 0, 0);
            c = __builtin_amdgcn_mfma_f32_16x16x32_bf16(T1, WB[tt][1], c, 0, 0, 0);
#pragma unroll
            for (int r = 0; r < 4; ++r) {
                float v = fmaxf(c[r] + bBl[tt], 0.0f);
                pt[wv * 16 + quad * 4 + r][tt * 16 + col] = v;
            }
        }
    } else {
        // inactive wave: zero its tile rows so the reduce sees zeros
        for (int c2 = 0; c2 < 4; ++c2)
#pragma unroll
            for (int r = 0; r < 4; ++r)
                pt[wv * 16 + quad * 4 + r][c2 * 16 + col] = 0.0f;
    }
    __syncthreads();

    // segmented reduce: thread (q,d) sums rows q*16..q*16+15 of dim d,
    // flushing one atomicAdd per graph run; d==0 thread also counts rows.
    int q = t >> 6;
    int d = t & 63;
    float acc = 0.0f;
    int   len = 0;
    int curg = sbatch[q * 16];
#pragma unroll
    for (int r = 0; r < 16; ++r) {
        int row = q * 16 + r;
        int g2 = sbatch[row];
        float v = pt[row][d];
        if (g2 != curg) {
            if (curg >= 0) {
                atomicAdd(&psum[curg * D + d], acc);
                if (d == 0) atomicAdd(&cnts[curg], (float)len);
            }
            acc = 0.0f; len = 0;
            curg = g2;
        }
        acc += v;
        len += 1;
    }
    if (curg >= 0) {
        atomicAdd(&psum[curg * D + d], acc);
        if (d == 0) atomicAdd(&cnts[curg], (float)len);
    }
}

// ---------------------------------------------------------------------------
// Head: mean from psum + cnts, single-step LSTM + FC + softmax.
// ---------------------------------------------------------------------------
__device__ __forceinline__ float sigmoidf_(float x) { return 1.0f / (1.0f + expf(-x)); }

__global__ __launch_bounds__(512) void head_kernel(
    const float* __restrict__ psum,   // [B,64] pooled sums
    const float* __restrict__ cnts,   // [B] node counts
    const float* __restrict__ w_ih,
    const float* __restrict__ w_hh,
    const float* __restrict__ b_ih,
    const float* __restrict__ b_hh,
    const float* __restrict__ fc_w,
    const float* __restrict__ fc_b,
    const float* __restrict__ h0,
    const float* __restrict__ c0,
    float*       __restrict__ out_probs,
    float*       __restrict__ out_h1,
    float*       __restrict__ out_c1)
{
    int b = blockIdx.x;
    int j = threadIdx.x;

    __shared__ float sp[D];
    __shared__ float sh[HL];
    __shared__ float gates[4 * HL];
    __shared__ float sh1[HL];
    __shared__ float slog[OUT];

    if (j < D) {
        sp[j] = psum[b * D + j] / fmaxf(cnts[b], 1.0f);
    } else if (j < D + HL) {
        sh[j - D] = h0[b * HL + (j - D)];
    }
    __syncthreads();

    {
        float acc = b_ih[j] + b_hh[j];
#pragma unroll
        for (int k = 0; k < D; ++k)  acc = fmaf(sp[k], w_ih[j * D + k], acc);
#pragma unroll
        for (int k = 0; k < HL; ++k) acc = fmaf(sh[k], w_hh[j * HL + k], acc);
        gates[j] = acc;
    }
    __syncthreads();

    if (j < HL) {
        float ig = gates[j];
        float fg = gates[HL + j];
        float gg = gates[2 * HL + j];
        float og = gates[3 * HL + j];
        float c  = sigmoidf_(fg) * c0[b * HL + j] + sigmoidf_(ig) * tanhf(gg);
        float hv = sigmoidf_(og) * tanhf(c);
        out_c1[b * HL + j] = c;
        out_h1[b * HL + j] = hv;
        sh1[j] = hv;
    }
    __syncthreads();

    if (j < OUT) {
        float a = fc_b[j];
#pragma unroll
        for (int k = 0; k < HL; ++k) a = fmaf(sh1[k], fc_w[j * HL + k], a);
        slog[j] = a;
    }
    __syncthreads();

    if (j < OUT) {
        float m = -1e30f;
#pragma unroll
        for (int k = 0; k < OUT; ++k) m = fmaxf(m, slog[k]);
        float s = 0.0f;
#pragma unroll
        for (int k = 0; k < OUT; ++k) s += expf(slog[k] - m);
        out_probs[b * OUT + j] = expf(slog[j] - m) / s;
    }
}

// ---------------------------------------------------------------------------
extern "C" void kernel_launch(void* const* d_in, const int* in_sizes, int n_in,
                              void* d_out, int out_size, void* d_ws, size_t ws_size,
                              hipStream_t stream)
{
    const float* x     = (const float*)d_in[0];
    const int*   ei    = (const int*)  d_in[1];
    const int*   batch = (const int*)  d_in[2];
    const float* w1    = (const float*)d_in[3];
    const float* b1    = (const float*)d_in[4];
    const float* w2    = (const float*)d_in[5];
    const float* b2    = (const float*)d_in[6];
    const float* w3    = (const float*)d_in[7];
    const float* b3    = (const float*)d_in[8];
    const float* w4    = (const float*)d_in[9];
    const float* b4    = (const float*)d_in[10];
    const float* w_ih  = (const float*)d_in[11];
    const float* w_hh  = (const float*)d_in[12];
    const float* b_ih  = (const float*)d_in[13];
    const float* b_hh  = (const float*)d_in[14];
    const float* fc_w  = (const float*)d_in[15];
    const float* fc_b  = (const float*)d_in[16];
    const float* h0    = (const float*)d_in[17];
    const float* c0    = (const float*)d_in[18];

    // workspace layout (~10 MB); h1 has N+16 rows (row ZROW = 0)
    const size_t NR = (size_t)N_NODES + 16;
    int* bincnt = (int*)d_ws;                                 // 256 ints
    unsigned* binbuf = (unsigned*)(bincnt + 256);             // BINS*BCAP
    unsigned short* h1 = (unsigned short*)(binbuf + (size_t)BINS * BCAP);
    unsigned short* wb = h1 + NR * D;                         // 4 x [64,64] bf16
    float* psum = (float*)(wb + 4 * D * D);                   // [B,64]
    float* cnts = psum + B * D;                               // [B]

    float* out_probs = (float*)d_out;
    float* out_h1    = out_probs + B * OUT;
    float* out_c1    = out_h1 + B * HL;

    // ---- bincnt zero (1 KB) + prologue (binA || weight cvt || init) ----
    hipMemsetAsync(bincnt, 0, 256 * sizeof(int), stream);
    pro_kernel<<<AB + 5, 256, 0, stream>>>(
        ei, bincnt, binbuf, w1, w2, w3, w4, wb, h1, psum, cnts);

    // ---- layer 1 (fused bucket-build + fp32 gather + MLP) ----
    gmlp_kernel<<<MB, 256, 0, stream>>>(x, bincnt, binbuf,
                                        wb, b1, wb + 4096, b2, h1);

    // ---- layer 2 (fused bucket-build + bf16 gather + MLP + pool) ----
    g2mlp_pool_kernel<<<MB, 256, 0, stream>>>(h1, bincnt, binbuf,
                                              wb + 8192, b3, wb + 12288, b4,
                                              batch, psum, cnts);

    // ---- head ----
    head_kernel<<<B, 512, 0, stream>>>(psum, cnts, w_ih, w_hh, b_ih, b_hh,
                                       fc_w, fc_b, h0, c0,
                                       out_probs, out_h1, out_c1);
}

// Round 5
// 215.467 us; speedup vs baseline: 1.0801x; 1.0801x over previous
//
#include <hip/hip_runtime.h>
#include <hip/hip_bf16.h>

#define N_NODES 50000
#define N_EDGES 800000
#define D 64
#define B 64
#define HL 128
#define OUT 32

#define CAP 64          // max in-degree capacity (Poisson(16): P(>=64) ~ 1e-18)
#define STP 72          // LDS transform tile row stride (ushorts)
#define ZROW N_NODES    // sentinel index (u16-safe: 50000 < 65536)

#define BINS 196        // ceil(N_NODES/256): coarse bins of 256 nodes (dst>>8)
#define EPB 4096        // edges per block in binA
#define LCAP 48         // per-(block,bin) LDS staging cap (mean 20.9, +5.9 sigma)
#define BCAP 4608       // per-bin global region cap (mean 4082)

#define AB 196          // binA blocks (196*4096 >= 800000)
#define CB 3125         // cvt blocks (N*D/4/256)
#define MB 782          // mlp blocks (64 nodes each)

typedef __attribute__((ext_vector_type(8))) short          short8;
typedef __attribute__((ext_vector_type(8))) unsigned short ushort8_t;
typedef __attribute__((ext_vector_type(4))) float          floatx4;

// bf16 helpers (RNE pack, cheap unpack)
__device__ __forceinline__ unsigned short f2bf(float f)
{
    unsigned u = __float_as_uint(f);
    u = (u + 0x7FFFu + ((u >> 16) & 1u)) >> 16;
    return (unsigned short)u;
}
__device__ __forceinline__ float bfLO(unsigned u) { return __uint_as_float(u << 16); }
__device__ __forceinline__ float bfHI(unsigned u) { return __uint_as_float(u & 0xffff0000u); }

// ---------------------------------------------------------------------------
// Prologue, block-range roles (independent work in one dispatch):
//   [0, AB)        : binA — bin edges by dst>>8 via LDS staging (4096 e/blk)
//   [AB, AB+CB)    : cvt x -> bf16 xb (first 64 also convert MLP weights)
//   AB+CB          : init — sentinel zero rows + psum/cnts zero
// bincnt is zeroed by a prior 1KB memset.
// ---------------------------------------------------------------------------
__global__ __launch_bounds__(256) void pro_kernel(
    const int*   __restrict__ ei,
    int*         __restrict__ bincnt,
    unsigned*    __restrict__ binbuf,
    const float* __restrict__ x, unsigned short* __restrict__ xb,
    const float* __restrict__ w1, const float* __restrict__ w2,
    const float* __restrict__ w3, const float* __restrict__ w4,
    unsigned short* __restrict__ wb,
    unsigned short* __restrict__ h1,
    float*       __restrict__ psum,
    float*       __restrict__ cnts)
{
    __shared__ int      lcnt[BINS];
    __shared__ int      gbase[BINS];
    __shared__ unsigned lbuf[BINS * LCAP];   // 36.8 KB

    int t = threadIdx.x;

    if (blockIdx.x < AB) {
        // ---------------- binA ----------------
        if (t < BINS) lcnt[t] = 0;
        __syncthreads();

        int base = blockIdx.x * EPB;
#pragma unroll 8
        for (int i = 0; i < EPB / 256; ++i) {
            int e = base + i * 256 + t;
            if (e < N_EDGES) {
                int s = ei[e];
                int d = ei[N_EDGES + e];
                int bin = d >> 8;
                unsigned pk = (unsigned)s | ((unsigned)(d & 255) << 16);
                int p = atomicAdd(&lcnt[bin], 1);
                if (p < LCAP) {
                    lbuf[bin * LCAP + p] = pk;
                } else {                          // statistically never
                    int q = atomicAdd(&bincnt[bin], 1);
                    if (q < BCAP) binbuf[bin * BCAP + q] = pk;
                }
            }
        }
        __syncthreads();

        if (t < BINS) {
            int m = lcnt[t]; m = (m < LCAP) ? m : LCAP;
            gbase[t] = (m > 0) ? atomicAdd(&bincnt[t], m) : 0;
        }
        __syncthreads();

        int wv = t >> 6, lane = t & 63;
        for (int b = wv; b < BINS; b += 4) {
            int m = lcnt[b]; m = (m < LCAP) ? m : LCAP;
            int gb = gbase[b];
            for (int j = lane; j < m; j += 64)
                if (gb + j < BCAP) binbuf[b * BCAP + gb + j] = lbuf[b * LCAP + j];
        }
    } else if (blockIdx.x < AB + CB) {
        // ---------------- cvt ----------------
        int cb = blockIdx.x - AB;
        int i = cb * 256 + t;                    // i < N*D/4
        const float4 v = reinterpret_cast<const float4*>(x)[i];
        ushort4 o;
        o.x = f2bf(v.x); o.y = f2bf(v.y); o.z = f2bf(v.z); o.w = f2bf(v.w);
        reinterpret_cast<ushort4*>(xb)[i] = o;

        if (cb < 64) {                           // 64*256 = 4*4096 weights
            int j = cb * 256 + t;
            int m = j >> 12, off = j & 4095;
            const float* src = (m == 0) ? w1 : (m == 1) ? w2 : (m == 2) ? w3 : w4;
            wb[j] = f2bf(src[off]);
        }
    } else {
        // ---------------- init ----------------
        if (t < D) {                             // sentinel zero rows
            xb[(size_t)ZROW * D + t] = 0;
            h1[(size_t)ZROW * D + t] = 0;
        }
#pragma unroll
        for (int k = 0; k < 16; ++k)             // psum[B*64] = 0
            psum[t * 16 + k] = 0.0f;
        if (t < B) cnts[t] = 0.0f;
    }
}

// ---------------------------------------------------------------------------
// Per-block LDS bucket build: the block's 64 nodes are one quarter of one
// 256-node bin. Scan the bin's packed-edge region, keep entries whose dlow
// falls in our quarter. Rows pre-filled with ZROW -> branchless gather.
// Must be called by ALL 256 threads (contains __syncthreads).
// ---------------------------------------------------------------------------
__device__ __forceinline__ void build_bucket64(
    const int*      __restrict__ bincnt,
    const unsigned* __restrict__ binbuf,
    unsigned short* lbkt,     // [64*CAP + 16] LDS
    int*            lc,       // [64] LDS
    int bn0, int t)
{
    {
        ushort8_t fill = {ZROW, ZROW, ZROW, ZROW, ZROW, ZROW, ZROW, ZROW};
        reinterpret_cast<ushort8_t*>(lbkt)[t]       = fill;
        reinterpret_cast<ushort8_t*>(lbkt)[t + 256] = fill;
    }
    if (t < 64) lc[t] = 0;
    __syncthreads();

    const int bin = bn0 >> 8;
    const int q   = (bn0 >> 6) & 3;              // quarter within the bin
    int m = bincnt[bin]; m = (m < BCAP) ? m : BCAP;
    const unsigned* src = binbuf + bin * BCAP;
    for (int j = t; j < m; j += 256) {
        unsigned pk = src[j];
        int dlow = (pk >> 16) & 255;
        if ((dlow >> 6) == q) {
            int r = dlow & 63;
            int p = atomicAdd(&lc[r], 1);
            if (p < CAP) lbkt[r * CAP + p] = (unsigned short)(pk & 0xFFFFu);
        }
    }
    __syncthreads();
}

// ---------------------------------------------------------------------------
// Gather, round-outer form for deep VMEM ILP: wave handles 16 nodes.
// Group g = lane>>4 owns node bn0+wv*16+b*4+g (b=0..3); lane c = lane&15
// owns dims 4c..4c+3 (uint2 = 8 B/lane). Round count = WAVE max of
// ceil(deg/8) over all 16 nodes; overshoot rounds read ZROW-padded bucket
// entries -> cached sentinel zero row. Per round, 4 LDS index reads and
// all 32 global loads issue before any accumulation consumes them, so a
// wave has ~1 serialized memory wait per round (vs 14 in the b-outer form).
// ---------------------------------------------------------------------------
__device__ __forceinline__ void gather16_bf16(
    const unsigned short* __restrict__ feat,
    const unsigned short* lbkt,          // [64*CAP] LDS (+pad)
    const int*            lc,            // [64] LDS
    unsigned short*       stw,           // wave's LDS tile, 16 rows x STP
    int bn0, int wv, int lane)
{
    const int g = lane >> 4;
    const int c = lane & 15;

    // wave-uniform round count
    int dmax = 0;
#pragma unroll
    for (int b = 0; b < 4; ++b) {
        int d = lc[wv * 16 + b * 4 + g];
        d = (d < CAP) ? d : CAP;
        dmax = (d > dmax) ? d : dmax;
    }
    int m = (dmax + 7) >> 3;
    {
        int t1 = __shfl_xor(m, 16); m = (t1 > m) ? t1 : m;
        int t2 = __shfl_xor(m, 32); m = (t2 > m) ? t2 : m;
    }

    // self rows
    float a[4][4];
#pragma unroll
    for (int b = 0; b < 4; ++b) {
        const int node = bn0 + wv * 16 + b * 4 + g;
        uint2 u = *reinterpret_cast<const uint2*>(feat + (size_t)node * D + 4 * c);
        a[b][0] = bfLO(u.x); a[b][1] = bfHI(u.x);
        a[b][2] = bfLO(u.y); a[b][3] = bfHI(u.y);
    }

    for (int r = 0; r < m; ++r) {
        ushort8_t idx[4];
#pragma unroll
        for (int b = 0; b < 4; ++b)
            idx[b] = *reinterpret_cast<const ushort8_t*>(
                lbkt + (wv * 16 + b * 4 + g) * CAP + r * 8);

        uint2 v[4][8];
#pragma unroll
        for (int b = 0; b < 4; ++b)
#pragma unroll
            for (int j = 0; j < 8; ++j)
                v[b][j] = *reinterpret_cast<const uint2*>(
                    feat + (size_t)idx[b][j] * D + 4 * c);

#pragma unroll
        for (int b = 0; b < 4; ++b)
#pragma unroll
            for (int j = 0; j < 8; ++j) {
                a[b][0] += bfLO(v[b][j].x); a[b][1] += bfHI(v[b][j].x);
                a[b][2] += bfLO(v[b][j].y); a[b][3] += bfHI(v[b][j].y);
            }
    }

#pragma unroll
    for (int b = 0; b < 4; ++b) {
        uint2 o;
        o.x = (unsigned)f2bf(a[b][0]) | ((unsigned)f2bf(a[b][1]) << 16);
        o.y = (unsigned)f2bf(a[b][2]) | ((unsigned)f2bf(a[b][3]) << 16);
        *reinterpret_cast<uint2*>(stw + (b * 4 + g) * STP + 4 * c) = o;
    }
}

// ---------------------------------------------------------------------------
// Fused bucket-build + gather + MLP layer 1 via MFMA (m89/m91 layouts).
// ---------------------------------------------------------------------------
__global__ __launch_bounds__(256) void gmlp_kernel(
    const unsigned short* __restrict__ feat,   // xb (bf16 rows, ZROW valid)
    const int*            __restrict__ bincnt,
    const unsigned*       __restrict__ binbuf,
    const unsigned short* __restrict__ wAb,
    const float*          __restrict__ bA,
    const unsigned short* __restrict__ wBb,
    const float*          __restrict__ bB,
    unsigned short*       __restrict__ outp)
{
    __shared__ int lc[64];
    __shared__ __align__(16) unsigned short lbkt[64 * CAP + 16];  // 8.2 KB
    __shared__ __align__(16) unsigned short st[4][16 * STP];      // 9.2 KB

    const int t    = threadIdx.x;
    const int wv   = t >> 6;
    const int lane = t & 63;
    const int quad = lane >> 4;
    const int col  = lane & 15;

    const int bn0 = blockIdx.x * 64;
    const int n0  = bn0 + wv * 16;

    build_bucket64(bincnt, binbuf, lbkt, lc, bn0, t);

    if (n0 >= N_NODES) return;                   // after barriers: safe

    float bAl[4], bBl[4];
#pragma unroll
    for (int tt = 0; tt < 4; ++tt) {
        bAl[tt] = bA[tt * 16 + col];
        bBl[tt] = bB[tt * 16 + col];
    }

    short8 WA[4][2], WB[4][2];
#pragma unroll
    for (int tt = 0; tt < 4; ++tt)
#pragma unroll
        for (int k = 0; k < 2; ++k) {
            WA[tt][k] = *reinterpret_cast<const short8*>(
                wAb + (tt * 16 + col) * D + k * 32 + quad * 8);
            WB[tt][k] = *reinterpret_cast<const short8*>(
                wBb + (tt * 16 + col) * D + k * 32 + quad * 8);
        }

    unsigned short* stw = &st[wv][0];

    gather16_bf16(feat, lbkt, lc, stw, bn0, wv, lane);

    short8 A0 = *reinterpret_cast<const short8*>(stw + col * STP + 0 * 32 + quad * 8);
    short8 A1 = *reinterpret_cast<const short8*>(stw + col * STP + 1 * 32 + quad * 8);

#pragma unroll
    for (int tt = 0; tt < 4; ++tt) {
        floatx4 c = {0.0f, 0.0f, 0.0f, 0.0f};
        c = __builtin_amdgcn_mfma_f32_16x16x32_bf16(A0, WA[tt][0], c, 0, 0, 0);
        c = __builtin_amdgcn_mfma_f32_16x16x32_bf16(A1, WA[tt][1], c, 0, 0, 0);
#pragma unroll
        for (int r = 0; r < 4; ++r) {
            float v = fmaxf(c[r] + bAl[tt], 0.0f);
            stw[(quad * 4 + r) * STP + tt * 16 + col] = f2bf(v);
        }
    }

    short8 T0 = *reinterpret_cast<const short8*>(stw + col * STP + 0 * 32 + quad * 8);
    short8 T1 = *reinterpret_cast<const short8*>(stw + col * STP + 1 * 32 + quad * 8);

#pragma unroll
    for (int tt = 0; tt < 4; ++tt) {
        floatx4 c = {0.0f, 0.0f, 0.0f, 0.0f};
        c = __builtin_amdgcn_mfma_f32_16x16x32_bf16(T0, WB[tt][0], c, 0, 0, 0);
        c = __builtin_amdgcn_mfma_f32_16x16x32_bf16(T1, WB[tt][1], c, 0, 0, 0);
#pragma unroll
        for (int r = 0; r < 4; ++r) {
            float v = fmaxf(c[r] + bBl[tt], 0.0f);
            outp[(size_t)(n0 + quad * 4 + r) * D + tt * 16 + col] = f2bf(v);
        }
    }
}

// ---------------------------------------------------------------------------
// Fused bucket-build + gather + MLP layer 2 + mean-pool numerator +
// per-graph node counts (for the head's mean).
// ---------------------------------------------------------------------------
__global__ __launch_bounds__(256) void g2mlp_pool_kernel(
    const unsigned short* __restrict__ feat,   // h1 (layer-1 output, bf16)
    const int*            __restrict__ bincnt,
    const unsigned*       __restrict__ binbuf,
    const unsigned short* __restrict__ wAb,
    const float*          __restrict__ bA,
    const unsigned short* __restrict__ wBb,
    const float*          __restrict__ bB,
    const int*            __restrict__ batch,  // [N] sorted
    float*                __restrict__ psum,   // [B,64] zero-initialized
    float*                __restrict__ cnts)   // [B] zero-initialized
{
    __shared__ int lc[64];
    __shared__ __align__(16) unsigned short lbkt[64 * CAP + 16];
    __shared__ __align__(16) unsigned short st[4][16 * STP];
    __shared__ float pt[64][D + 1];            // block's 64-node output tile
    __shared__ int   sbatch[64];

    const int t    = threadIdx.x;
    const int wv   = t >> 6;
    const int lane = t & 63;
    const int quad = lane >> 4;
    const int col  = lane & 15;

    const int bn0 = blockIdx.x * 64;
    const int n0  = bn0 + wv * 16;
    const bool active = (n0 < N_NODES);

    if (t < 64) {
        int n = bn0 + t;
        sbatch[t] = (n < N_NODES) ? batch[n] : -1;
    }
    // (sbatch covered by build_bucket64's first __syncthreads)

    build_bucket64(bincnt, binbuf, lbkt, lc, bn0, t);

    if (active) {
        float bAl[4], bBl[4];
#pragma unroll
        for (int tt = 0; tt < 4; ++tt) {
            bAl[tt] = bA[tt * 16 + col];
            bBl[tt] = bB[tt * 16 + col];
        }

        short8 WA[4][2], WB[4][2];
#pragma unroll
        for (int tt = 0; tt < 4; ++tt)
#pragma unroll
            for (int k = 0; k < 2; ++k) {
                WA[tt][k] = *reinterpret_cast<const short8*>(
                    wAb + (tt * 16 + col) * D + k * 32 + quad * 8);
                WB[tt][k] = *reinterpret_cast<const short8*>(
                    wBb + (tt * 16 + col) * D + k * 32 + quad * 8);
            }

        unsigned short* stw = &st[wv][0];

        gather16_bf16(feat, lbkt, lc, stw, bn0, wv, lane);

        short8 A0 = *reinterpret_cast<const short8*>(stw + col * STP + 0 * 32 + quad * 8);
        short8 A1 = *reinterpret_cast<const short8*>(stw + col * STP + 1 * 32 + quad * 8);

#pragma unroll
        for (int tt = 0; tt < 4; ++tt) {
            floatx4 c = {0.0f, 0.0f, 0.0f, 0.0f};
            c = __builtin_amdgcn_mfma_f32_16x16x32_bf16(A0, WA[tt][0], c, 0, 0, 0);
            c = __builtin_amdgcn_mfma_f32_16x16x32_bf16(A1, WA[tt][1], c, 0, 0, 0);
#pragma unroll
            for (int r = 0; r < 4; ++r) {
                float v = fmaxf(c[r] + bAl[tt], 0.0f);
                stw[(quad * 4 + r) * STP + tt * 16 + col] = f2bf(v);
            }
        }

        short8 T0 = *reinterpret_cast<const short8*>(stw + col * STP + 0 * 32 + quad * 8);
        short8 T1 = *reinterpret_cast<const short8*>(stw + col * STP + 1 * 32 + quad * 8);

#pragma unroll
        for (int tt = 0; tt < 4; ++tt) {
            floatx4 c = {0.0f, 0.0f, 0.0f, 0.0f};
            c = __builtin_amdgcn_mfma_f32_16x16x32_bf16(T0, WB[tt][0], c, 0, 0, 0);
            c = __builtin_amdgcn_mfma_f32_16x16x32_bf16(T1, WB[tt][1], c, 0, 0, 0);
#pragma unroll
            for (int r = 0; r < 4; ++r) {
                float v = fmaxf(c[r] + bBl[tt], 0.0f);
                pt[wv * 16 + quad * 4 + r][tt * 16 + col] = v;
            }
        }
    } else {
        // inactive wave: zero its tile rows so the reduce sees zeros
        for (int c2 = 0; c2 < 4; ++c2)
#pragma unroll
            for (int r = 0; r < 4; ++r)
                pt[wv * 16 + quad * 4 + r][c2 * 16 + col] = 0.0f;
    }
    __syncthreads();

    // segmented reduce: thread (q,d) sums rows q*16..q*16+15 of dim d,
    // flushing one atomicAdd per graph run; d==0 thread also counts rows.
    int q = t >> 6;
    int d = t & 63;
    float acc = 0.0f;
    int   len = 0;
    int curg = sbatch[q * 16];
#pragma unroll
    for (int r = 0; r < 16; ++r) {
        int row = q * 16 + r;
        int g2 = sbatch[row];
        float v = pt[row][d];
        if (g2 != curg) {
            if (curg >= 0) {
                atomicAdd(&psum[curg * D + d], acc);
                if (d == 0) atomicAdd(&cnts[curg], (float)len);
            }
            acc = 0.0f; len = 0;
            curg = g2;
        }
        acc += v;
        len += 1;
    }
    if (curg >= 0) {
        atomicAdd(&psum[curg * D + d], acc);
        if (d == 0) atomicAdd(&cnts[curg], (float)len);
    }
}

// ---------------------------------------------------------------------------
// Head: mean from psum + cnts, single-step LSTM + FC + softmax.
// ---------------------------------------------------------------------------
__device__ __forceinline__ float sigmoidf_(float x) { return 1.0f / (1.0f + expf(-x)); }

__global__ __launch_bounds__(512) void head_kernel(
    const float* __restrict__ psum,   // [B,64] pooled sums
    const float* __restrict__ cnts,   // [B] node counts
    const float* __restrict__ w_ih,
    const float* __restrict__ w_hh,
    const float* __restrict__ b_ih,
    const float* __restrict__ b_hh,
    const float* __restrict__ fc_w,
    const float* __restrict__ fc_b,
    const float* __restrict__ h0,
    const float* __restrict__ c0,
    float*       __restrict__ out_probs,
    float*       __restrict__ out_h1,
    float*       __restrict__ out_c1)
{
    int b = blockIdx.x;
    int j = threadIdx.x;

    __shared__ float sp[D];
    __shared__ float sh[HL];
    __shared__ float gates[4 * HL];
    __shared__ float sh1[HL];
    __shared__ float slog[OUT];

    if (j < D) {
        sp[j] = psum[b * D + j] / fmaxf(cnts[b], 1.0f);
    } else if (j < D + HL) {
        sh[j - D] = h0[b * HL + (j - D)];
    }
    __syncthreads();

    {
        float acc = b_ih[j] + b_hh[j];
#pragma unroll
        for (int k = 0; k < D; ++k)  acc = fmaf(sp[k], w_ih[j * D + k], acc);
#pragma unroll
        for (int k = 0; k < HL; ++k) acc = fmaf(sh[k], w_hh[j * HL + k], acc);
        gates[j] = acc;
    }
    __syncthreads();

    if (j < HL) {
        float ig = gates[j];
        float fg = gates[HL + j];
        float gg = gates[2 * HL + j];
        float og = gates[3 * HL + j];
        float c  = sigmoidf_(fg) * c0[b * HL + j] + sigmoidf_(ig) * tanhf(gg);
        float hv = sigmoidf_(og) * tanhf(c);
        out_c1[b * HL + j] = c;
        out_h1[b * HL + j] = hv;
        sh1[j] = hv;
    }
    __syncthreads();

    if (j < OUT) {
        float a = fc_b[j];
#pragma unroll
        for (int k = 0; k < HL; ++k) a = fmaf(sh1[k], fc_w[j * HL + k], a);
        slog[j] = a;
    }
    __syncthreads();

    if (j < OUT) {
        float m = -1e30f;
#pragma unroll
        for (int k = 0; k < OUT; ++k) m = fmaxf(m, slog[k]);
        float s = 0.0f;
#pragma unroll
        for (int k = 0; k < OUT; ++k) s += expf(slog[k] - m);
        out_probs[b * OUT + j] = expf(slog[j] - m) / s;
    }
}

// ---------------------------------------------------------------------------
extern "C" void kernel_launch(void* const* d_in, const int* in_sizes, int n_in,
                              void* d_out, int out_size, void* d_ws, size_t ws_size,
                              hipStream_t stream)
{
    const float* x     = (const float*)d_in[0];
    const int*   ei    = (const int*)  d_in[1];
    const int*   batch = (const int*)  d_in[2];
    const float* w1    = (const float*)d_in[3];
    const float* b1    = (const float*)d_in[4];
    const float* w2    = (const float*)d_in[5];
    const float* b2    = (const float*)d_in[6];
    const float* w3    = (const float*)d_in[7];
    const float* b3    = (const float*)d_in[8];
    const float* w4    = (const float*)d_in[9];
    const float* b4    = (const float*)d_in[10];
    const float* w_ih  = (const float*)d_in[11];
    const float* w_hh  = (const float*)d_in[12];
    const float* b_ih  = (const float*)d_in[13];
    const float* b_hh  = (const float*)d_in[14];
    const float* fc_w  = (const float*)d_in[15];
    const float* fc_b  = (const float*)d_in[16];
    const float* h0    = (const float*)d_in[17];
    const float* c0    = (const float*)d_in[18];

    // workspace layout (~17 MB); xb/h1 have N+16 rows (row ZROW = 0)
    const size_t NR = (size_t)N_NODES + 16;
    int* bincnt = (int*)d_ws;                                 // 256 ints
    unsigned* binbuf = (unsigned*)(bincnt + 256);             // BINS*BCAP
    unsigned short* xb = (unsigned short*)(binbuf + (size_t)BINS * BCAP);
    unsigned short* h1 = xb + NR * D;                         // [NR,64] mlp1 out
    unsigned short* wb = h1 + NR * D;                         // 4 x [64,64] bf16
    float* psum = (float*)(wb + 4 * D * D);                   // [B,64]
    float* cnts = psum + B * D;                               // [B]

    float* out_probs = (float*)d_out;
    float* out_h1    = out_probs + B * OUT;
    float* out_c1    = out_h1 + B * HL;

    // ---- bincnt zero (1 KB) + prologue (binA || cvt || init) ----
    hipMemsetAsync(bincnt, 0, 256 * sizeof(int), stream);
    pro_kernel<<<AB + CB + 1, 256, 0, stream>>>(
        ei, bincnt, binbuf, x, xb, w1, w2, w3, w4, wb, h1, psum, cnts);

    // ---- layer 1 (fused bucket-build + gather + MLP) ----
    gmlp_kernel<<<MB, 256, 0, stream>>>(xb, bincnt, binbuf,
                                        wb, b1, wb + 4096, b2, h1);

    // ---- layer 2 (fused bucket-build + gather + MLP + pool) ----
    g2mlp_pool_kernel<<<MB, 256, 0, stream>>>(h1, bincnt, binbuf,
                                              wb + 8192, b3, wb + 12288, b4,
                                              batch, psum, cnts);

    // ---- head ----
    head_kernel<<<B, 512, 0, stream>>>(psum, cnts, w_ih, w_hh, b_ih, b_hh,
                                       fc_w, fc_b, h0, c0,
                                       out_probs, out_h1, out_c1);
}

// Round 6
// 209.367 us; speedup vs baseline: 1.1116x; 1.0291x over previous
//
#include <hip/hip_runtime.h>
#include <hip/hip_bf16.h>

#define N_NODES 50000
#define N_EDGES 800000
#define D 64
#define B 64
#define HL 128
#define OUT 32

#define CAP 64          // max in-degree capacity (Poisson(16): P(>=64) ~ 1e-18)
#define STP 72          // LDS transform tile row stride (ushorts)
#define ZROW N_NODES    // sentinel index (u16-safe: 50000 < 65536)

#define BINS 196        // ceil(N_NODES/256): coarse bins of 256 nodes (dst>>8)
#define EPB 2048        // edges per block in binA (R3-proven)
#define LCAP 48         // per-(block,bin) LDS staging cap
#define BCAP 4608       // per-bin global region cap (mean 4082)

#define AB 391          // binA blocks (391*2048 >= 800000)
#define CB 3125         // cvt blocks (N*D/4/256)
#define MB 782          // mlp blocks (64 nodes each)

typedef __attribute__((ext_vector_type(8))) short          short8;
typedef __attribute__((ext_vector_type(8))) unsigned short ushort8_t;
typedef __attribute__((ext_vector_type(4))) float          floatx4;

// bf16 helpers (RNE pack, cheap unpack)
__device__ __forceinline__ unsigned short f2bf(float f)
{
    unsigned u = __float_as_uint(f);
    u = (u + 0x7FFFu + ((u >> 16) & 1u)) >> 16;
    return (unsigned short)u;
}
__device__ __forceinline__ float bfLO(unsigned u) { return __uint_as_float(u << 16); }
__device__ __forceinline__ float bfHI(unsigned u) { return __uint_as_float(u & 0xffff0000u); }

// ---------------------------------------------------------------------------
// Prologue, block-range roles (independent work in one dispatch):
//   [0, AB)        : binA — bin edges by dst>>8 via LDS staging (2048 e/blk)
//   [AB, AB+CB)    : cvt x -> bf16 xb (first 64 also convert MLP weights)
//   AB+CB          : init — sentinel zero rows + psum/cnts zero
// bincnt is zeroed by a prior 1KB memset.
// ---------------------------------------------------------------------------
__global__ __launch_bounds__(256) void pro_kernel(
    const int*   __restrict__ ei,
    int*         __restrict__ bincnt,
    unsigned*    __restrict__ binbuf,
    const float* __restrict__ x, unsigned short* __restrict__ xb,
    const float* __restrict__ w1, const float* __restrict__ w2,
    const float* __restrict__ w3, const float* __restrict__ w4,
    unsigned short* __restrict__ wb,
    unsigned short* __restrict__ h1,
    float*       __restrict__ psum,
    float*       __restrict__ cnts)
{
    __shared__ int      lcnt[BINS];
    __shared__ int      gbase[BINS];
    __shared__ unsigned lbuf[BINS * LCAP];   // 36.8 KB

    int t = threadIdx.x;

    if (blockIdx.x < AB) {
        // ---------------- binA ----------------
        if (t < BINS) lcnt[t] = 0;
        __syncthreads();

        int base = blockIdx.x * EPB;
#pragma unroll
        for (int i = 0; i < EPB / 256; ++i) {
            int e = base + i * 256 + t;
            if (e < N_EDGES) {
                int s = ei[e];
                int d = ei[N_EDGES + e];
                int bin = d >> 8;
                unsigned pk = (unsigned)s | ((unsigned)(d & 255) << 16);
                int p = atomicAdd(&lcnt[bin], 1);
                if (p < LCAP) {
                    lbuf[bin * LCAP + p] = pk;
                } else {                          // statistically never
                    int q = atomicAdd(&bincnt[bin], 1);
                    if (q < BCAP) binbuf[bin * BCAP + q] = pk;
                }
            }
        }
        __syncthreads();

        if (t < BINS) {
            int m = lcnt[t]; m = (m < LCAP) ? m : LCAP;
            gbase[t] = (m > 0) ? atomicAdd(&bincnt[t], m) : 0;
        }
        __syncthreads();

        int wv = t >> 6, lane = t & 63;
        for (int b = wv; b < BINS; b += 4) {
            int m = lcnt[b]; m = (m < LCAP) ? m : LCAP;
            int gb = gbase[b];
            for (int j = lane; j < m; j += 64)
                if (gb + j < BCAP) binbuf[b * BCAP + gb + j] = lbuf[b * LCAP + j];
        }
    } else if (blockIdx.x < AB + CB) {
        // ---------------- cvt ----------------
        int cb = blockIdx.x - AB;
        int i = cb * 256 + t;                    // i < N*D/4
        const float4 v = reinterpret_cast<const float4*>(x)[i];
        ushort4 o;
        o.x = f2bf(v.x); o.y = f2bf(v.y); o.z = f2bf(v.z); o.w = f2bf(v.w);
        reinterpret_cast<ushort4*>(xb)[i] = o;

        if (cb < 64) {                           // 64*256 = 4*4096 weights
            int j = cb * 256 + t;
            int m = j >> 12, off = j & 4095;
            const float* src = (m == 0) ? w1 : (m == 1) ? w2 : (m == 2) ? w3 : w4;
            wb[j] = f2bf(src[off]);
        }
    } else {
        // ---------------- init ----------------
        if (t < D) {                             // sentinel zero rows
            xb[(size_t)ZROW * D + t] = 0;
            h1[(size_t)ZROW * D + t] = 0;
        }
#pragma unroll
        for (int k = 0; k < 16; ++k)             // psum[B*64] = 0
            psum[t * 16 + k] = 0.0f;
        if (t < B) cnts[t] = 0.0f;
    }
}

// ---------------------------------------------------------------------------
// Per-block LDS bucket build (512 threads): the block's 64 nodes are one
// quarter of one 256-node bin. Scan the bin's packed-edge region, keep
// entries whose dlow falls in our quarter. Rows pre-filled with ZROW ->
// branchless gather. Must be called by ALL 512 threads (has barriers).
// ---------------------------------------------------------------------------
__device__ __forceinline__ void build_bucket64(
    const int*      __restrict__ bincnt,
    const unsigned* __restrict__ binbuf,
    unsigned short* lbkt,     // [64*CAP + 16] LDS
    int*            lc,       // [64] LDS
    int bn0, int t)
{
    {
        ushort8_t fill = {ZROW, ZROW, ZROW, ZROW, ZROW, ZROW, ZROW, ZROW};
        for (int i = t; i < (64 * CAP + 16) / 8; i += 512)
            reinterpret_cast<ushort8_t*>(lbkt)[i] = fill;
    }
    if (t < 64) lc[t] = 0;
    __syncthreads();

    const int bin = bn0 >> 8;
    const int q   = (bn0 >> 6) & 3;              // quarter within the bin
    int m = bincnt[bin]; m = (m < BCAP) ? m : BCAP;
    const unsigned* src = binbuf + bin * BCAP;
    for (int j = t; j < m; j += 512) {
        unsigned pk = src[j];
        int dlow = (pk >> 16) & 255;
        if ((dlow >> 6) == q) {
            int r = dlow & 63;
            int p = atomicAdd(&lc[r], 1);
            if (p < CAP) lbkt[r * CAP + p] = (unsigned short)(pk & 0xFFFFu);
        }
    }
    __syncthreads();
}

// ---------------------------------------------------------------------------
// Gather (R3 b-outer form, 8 nodes/wave): wave wv owns nodes
// [bn0+wv*8, bn0+wv*8+8). Group g = lane>>4 owns node wv*8+b*4+g (b=0..1);
// lane c = lane&15 owns dims 4c..4c+3 (uint2 = 8 B/lane). Per-b round count
// = wave max of ceil(deg/8) over its 4 nodes; overshoot rounds read
// ZROW-padded bucket entries -> cached sentinel zero row. Software-pipelined
// index loads. Output row goes to tile (wv>>1), row (wv&1)*8+b*4+g.
// ---------------------------------------------------------------------------
__device__ __forceinline__ void gather8_bf16(
    const unsigned short* __restrict__ feat,
    const unsigned short* lbkt,          // [64*CAP] LDS (+pad)
    const int*            lc,            // [64] LDS
    unsigned short*       stbase,        // &st[0][0]
    int bn0, int wv, int lane)
{
    const int g = lane >> 4;
    const int c = lane & 15;

#pragma unroll
    for (int b = 0; b < 2; ++b) {
        const int rloc = wv * 8 + b * 4 + g;
        const int node = bn0 + rloc;
        int deg = lc[rloc];
        deg = (deg < CAP) ? deg : CAP;
        int m = (deg + 7) >> 3;
        {   // wave-max over the 4 groups
            int t1 = __shfl_xor(m, 16); m = (t1 > m) ? t1 : m;
            int t2 = __shfl_xor(m, 32); m = (t2 > m) ? t2 : m;
        }

        const unsigned short* bkt = lbkt + rloc * CAP;

        // self row
        uint2 u = *reinterpret_cast<const uint2*>(feat + (size_t)node * D + 4 * c);
        float a0 = bfLO(u.x), a1 = bfHI(u.x);
        float a2 = bfLO(u.y), a3 = bfHI(u.y);

        ushort8_t idx = *reinterpret_cast<const ushort8_t*>(bkt);
        for (int r = 0; r < m; ++r) {
            ushort8_t nxt = *reinterpret_cast<const ushort8_t*>(bkt + (r + 1) * 8);
#pragma unroll
            for (int j = 0; j < 8; ++j) {
                uint2 v = *reinterpret_cast<const uint2*>(
                    feat + (size_t)idx[j] * D + 4 * c);
                a0 += bfLO(v.x); a1 += bfHI(v.x);
                a2 += bfLO(v.y); a3 += bfHI(v.y);
            }
            idx = nxt;
        }

        const int tile = wv >> 1;
        const int row  = (wv & 1) * 8 + b * 4 + g;
        uint2 o;
        o.x = (unsigned)f2bf(a0) | ((unsigned)f2bf(a1) << 16);
        o.y = (unsigned)f2bf(a2) | ((unsigned)f2bf(a3) << 16);
        *reinterpret_cast<uint2*>(stbase + (tile * 16 + row) * STP + 4 * c) = o;
    }
}

// ---------------------------------------------------------------------------
// Fused bucket-build + gather (8 waves) + MLP layer 1 (waves 0-3) via MFMA.
// ---------------------------------------------------------------------------
__global__ __launch_bounds__(512) void gmlp_kernel(
    const unsigned short* __restrict__ feat,   // xb (bf16 rows, ZROW valid)
    const int*            __restrict__ bincnt,
    const unsigned*       __restrict__ binbuf,
    const unsigned short* __restrict__ wAb,
    const float*          __restrict__ bA,
    const unsigned short* __restrict__ wBb,
    const float*          __restrict__ bB,
    unsigned short*       __restrict__ outp)
{
    __shared__ int lc[64];
    __shared__ __align__(16) unsigned short lbkt[64 * CAP + 16];  // 8.2 KB
    __shared__ __align__(16) unsigned short st[4][16 * STP];      // 9.2 KB

    const int t    = threadIdx.x;
    const int wv   = t >> 6;
    const int lane = t & 63;
    const int quad = lane >> 4;
    const int col  = lane & 15;

    const int bn0 = blockIdx.x * 64;

    build_bucket64(bincnt, binbuf, lbkt, lc, bn0, t);

    if (bn0 + wv * 8 < N_NODES)
        gather8_bf16(feat, lbkt, lc, &st[0][0], bn0, wv, lane);
    __syncthreads();

    if (wv >= 4) return;                         // no barriers after this
    const int n0 = bn0 + wv * 16;
    if (n0 >= N_NODES) return;

    float bAl[4], bBl[4];
#pragma unroll
    for (int tt = 0; tt < 4; ++tt) {
        bAl[tt] = bA[tt * 16 + col];
        bBl[tt] = bB[tt * 16 + col];
    }

    short8 WA[4][2], WB[4][2];
#pragma unroll
    for (int tt = 0; tt < 4; ++tt)
#pragma unroll
        for (int k = 0; k < 2; ++k) {
            WA[tt][k] = *reinterpret_cast<const short8*>(
                wAb + (tt * 16 + col) * D + k * 32 + quad * 8);
            WB[tt][k] = *reinterpret_cast<const short8*>(
                wBb + (tt * 16 + col) * D + k * 32 + quad * 8);
        }

    unsigned short* stw = &st[wv][0];

    short8 A0 = *reinterpret_cast<const short8*>(stw + col * STP + 0 * 32 + quad * 8);
    short8 A1 = *reinterpret_cast<const short8*>(stw + col * STP + 1 * 32 + quad * 8);

#pragma unroll
    for (int tt = 0; tt < 4; ++tt) {
        floatx4 c = {0.0f, 0.0f, 0.0f, 0.0f};
        c = __builtin_amdgcn_mfma_f32_16x16x32_bf16(A0, WA[tt][0], c, 0, 0, 0);
        c = __builtin_amdgcn_mfma_f32_16x16x32_bf16(A1, WA[tt][1], c, 0, 0, 0);
#pragma unroll
        for (int r = 0; r < 4; ++r) {
            float v = fmaxf(c[r] + bAl[tt], 0.0f);
            stw[(quad * 4 + r) * STP + tt * 16 + col] = f2bf(v);
        }
    }

    short8 T0 = *reinterpret_cast<const short8*>(stw + col * STP + 0 * 32 + quad * 8);
    short8 T1 = *reinterpret_cast<const short8*>(stw + col * STP + 1 * 32 + quad * 8);

#pragma unroll
    for (int tt = 0; tt < 4; ++tt) {
        floatx4 c = {0.0f, 0.0f, 0.0f, 0.0f};
        c = __builtin_amdgcn_mfma_f32_16x16x32_bf16(T0, WB[tt][0], c, 0, 0, 0);
        c = __builtin_amdgcn_mfma_f32_16x16x32_bf16(T1, WB[tt][1], c, 0, 0, 0);
#pragma unroll
        for (int r = 0; r < 4; ++r) {
            float v = fmaxf(c[r] + bBl[tt], 0.0f);
            outp[(size_t)(n0 + quad * 4 + r) * D + tt * 16 + col] = f2bf(v);
        }
    }
}

// ---------------------------------------------------------------------------
// Fused bucket-build + gather (8 waves) + MLP layer 2 (waves 0-3) +
// mean-pool numerator + per-graph node counts.
// ---------------------------------------------------------------------------
__global__ __launch_bounds__(512) void g2mlp_pool_kernel(
    const unsigned short* __restrict__ feat,   // h1 (layer-1 output, bf16)
    const int*            __restrict__ bincnt,
    const unsigned*       __restrict__ binbuf,
    const unsigned short* __restrict__ wAb,
    const float*          __restrict__ bA,
    const unsigned short* __restrict__ wBb,
    const float*          __restrict__ bB,
    const int*            __restrict__ batch,  // [N] sorted
    float*                __restrict__ psum,   // [B,64] zero-initialized
    float*                __restrict__ cnts)   // [B] zero-initialized
{
    __shared__ int lc[64];
    __shared__ __align__(16) unsigned short lbkt[64 * CAP + 16];
    __shared__ __align__(16) unsigned short st[4][16 * STP];
    __shared__ float pt[64][D + 1];            // block's 64-node output tile
    __shared__ int   sbatch[64];

    const int t    = threadIdx.x;
    const int wv   = t >> 6;
    const int lane = t & 63;
    const int quad = lane >> 4;
    const int col  = lane & 15;

    const int bn0 = blockIdx.x * 64;

    if (t < 64) {
        int n = bn0 + t;
        sbatch[t] = (n < N_NODES) ? batch[n] : -1;
    }
    // (sbatch covered by build_bucket64's first __syncthreads)

    build_bucket64(bincnt, binbuf, lbkt, lc, bn0, t);

    if (bn0 + wv * 8 < N_NODES)
        gather8_bf16(feat, lbkt, lc, &st[0][0], bn0, wv, lane);
    __syncthreads();

    if (wv < 4) {
        const int n0 = bn0 + wv * 16;
        if (n0 < N_NODES) {
            float bAl[4], bBl[4];
#pragma unroll
            for (int tt = 0; tt < 4; ++tt) {
                bAl[tt] = bA[tt * 16 + col];
                bBl[tt] = bB[tt * 16 + col];
            }

            short8 WA[4][2], WB[4][2];
#pragma unroll
            for (int tt = 0; tt < 4; ++tt)
#pragma unroll
                for (int k = 0; k < 2; ++k) {
                    WA[tt][k] = *reinterpret_cast<const short8*>(
                        wAb + (tt * 16 + col) * D + k * 32 + quad * 8);
                    WB[tt][k] = *reinterpret_cast<const short8*>(
                        wBb + (tt * 16 + col) * D + k * 32 + quad * 8);
                }

            unsigned short* stw = &st[wv][0];

            short8 A0 = *reinterpret_cast<const short8*>(stw + col * STP + 0 * 32 + quad * 8);
            short8 A1 = *reinterpret_cast<const short8*>(stw + col * STP + 1 * 32 + quad * 8);

#pragma unroll
            for (int tt = 0; tt < 4; ++tt) {
                floatx4 c = {0.0f, 0.0f, 0.0f, 0.0f};
                c = __builtin_amdgcn_mfma_f32_16x16x32_bf16(A0, WA[tt][0], c, 0, 0, 0);
                c = __builtin_amdgcn_mfma_f32_16x16x32_bf16(A1, WA[tt][1], c, 0, 0, 0);
#pragma unroll
                for (int r = 0; r < 4; ++r) {
                    float v = fmaxf(c[r] + bAl[tt], 0.0f);
                    stw[(quad * 4 + r) * STP + tt * 16 + col] = f2bf(v);
                }
            }

            short8 T0 = *reinterpret_cast<const short8*>(stw + col * STP + 0 * 32 + quad * 8);
            short8 T1 = *reinterpret_cast<const short8*>(stw + col * STP + 1 * 32 + quad * 8);

#pragma unroll
            for (int tt = 0; tt < 4; ++tt) {
                floatx4 c = {0.0f, 0.0f, 0.0f, 0.0f};
                c = __builtin_amdgcn_mfma_f32_16x16x32_bf16(T0, WB[tt][0], c, 0, 0, 0);
                c = __builtin_amdgcn_mfma_f32_16x16x32_bf16(T1, WB[tt][1], c, 0, 0, 0);
#pragma unroll
                for (int r = 0; r < 4; ++r) {
                    float v = fmaxf(c[r] + bBl[tt], 0.0f);
                    pt[wv * 16 + quad * 4 + r][tt * 16 + col] = v;
                }
            }
        } else {
            // inactive tile: zero its rows so the reduce sees zeros
            for (int c2 = 0; c2 < 4; ++c2)
#pragma unroll
                for (int r = 0; r < 4; ++r)
                    pt[wv * 16 + quad * 4 + r][c2 * 16 + col] = 0.0f;
        }
    }
    __syncthreads();

    // segmented reduce (first 256 threads): thread (q,d) sums rows
    // q*16..q*16+15 of dim d, one atomicAdd per graph run; d==0 counts rows.
    if (t < 256) {
        int q = t >> 6;
        int d = t & 63;
        float acc = 0.0f;
        int   len = 0;
        int curg = sbatch[q * 16];
#pragma unroll
        for (int r = 0; r < 16; ++r) {
            int row = q * 16 + r;
            int g2 = sbatch[row];
            float v = pt[row][d];
            if (g2 != curg) {
                if (curg >= 0) {
                    atomicAdd(&psum[curg * D + d], acc);
                    if (d == 0) atomicAdd(&cnts[curg], (float)len);
                }
                acc = 0.0f; len = 0;
                curg = g2;
            }
            acc += v;
            len += 1;
        }
        if (curg >= 0) {
            atomicAdd(&psum[curg * D + d], acc);
            if (d == 0) atomicAdd(&cnts[curg], (float)len);
        }
    }
}

// ---------------------------------------------------------------------------
// Head: mean from psum + cnts, single-step LSTM + FC + softmax.
// ---------------------------------------------------------------------------
__device__ __forceinline__ float sigmoidf_(float x) { return 1.0f / (1.0f + expf(-x)); }

__global__ __launch_bounds__(512) void head_kernel(
    const float* __restrict__ psum,   // [B,64] pooled sums
    const float* __restrict__ cnts,   // [B] node counts
    const float* __restrict__ w_ih,
    const float* __restrict__ w_hh,
    const float* __restrict__ b_ih,
    const float* __restrict__ b_hh,
    const float* __restrict__ fc_w,
    const float* __restrict__ fc_b,
    const float* __restrict__ h0,
    const float* __restrict__ c0,
    float*       __restrict__ out_probs,
    float*       __restrict__ out_h1,
    float*       __restrict__ out_c1)
{
    int b = blockIdx.x;
    int j = threadIdx.x;

    __shared__ float sp[D];
    __shared__ float sh[HL];
    __shared__ float gates[4 * HL];
    __shared__ float sh1[HL];
    __shared__ float slog[OUT];

    if (j < D) {
        sp[j] = psum[b * D + j] / fmaxf(cnts[b], 1.0f);
    } else if (j < D + HL) {
        sh[j - D] = h0[b * HL + (j - D)];
    }
    __syncthreads();

    {
        float acc = b_ih[j] + b_hh[j];
#pragma unroll
        for (int k = 0; k < D; ++k)  acc = fmaf(sp[k], w_ih[j * D + k], acc);
#pragma unroll
        for (int k = 0; k < HL; ++k) acc = fmaf(sh[k], w_hh[j * HL + k], acc);
        gates[j] = acc;
    }
    __syncthreads();

    if (j < HL) {
        float ig = gates[j];
        float fg = gates[HL + j];
        float gg = gates[2 * HL + j];
        float og = gates[3 * HL + j];
        float c  = sigmoidf_(fg) * c0[b * HL + j] + sigmoidf_(ig) * tanhf(gg);
        float hv = sigmoidf_(og) * tanhf(c);
        out_c1[b * HL + j] = c;
        out_h1[b * HL + j] = hv;
        sh1[j] = hv;
    }
    __syncthreads();

    if (j < OUT) {
        float a = fc_b[j];
#pragma unroll
        for (int k = 0; k < HL; ++k) a = fmaf(sh1[k], fc_w[j * HL + k], a);
        slog[j] = a;
    }
    __syncthreads();

    if (j < OUT) {
        float m = -1e30f;
#pragma unroll
        for (int k = 0; k < OUT; ++k) m = fmaxf(m, slog[k]);
        float s = 0.0f;
#pragma unroll
        for (int k = 0; k < OUT; ++k) s += expf(slog[k] - m);
        out_probs[b * OUT + j] = expf(slog[j] - m) / s;
    }
}

// ---------------------------------------------------------------------------
extern "C" void kernel_launch(void* const* d_in, const int* in_sizes, int n_in,
                              void* d_out, int out_size, void* d_ws, size_t ws_size,
                              hipStream_t stream)
{
    const float* x     = (const float*)d_in[0];
    const int*   ei    = (const int*)  d_in[1];
    const int*   batch = (const int*)  d_in[2];
    const float* w1    = (const float*)d_in[3];
    const float* b1    = (const float*)d_in[4];
    const float* w2    = (const float*)d_in[5];
    const float* b2    = (const float*)d_in[6];
    const float* w3    = (const float*)d_in[7];
    const float* b3    = (const float*)d_in[8];
    const float* w4    = (const float*)d_in[9];
    const float* b4    = (const float*)d_in[10];
    const float* w_ih  = (const float*)d_in[11];
    const float* w_hh  = (const float*)d_in[12];
    const float* b_ih  = (const float*)d_in[13];
    const float* b_hh  = (const float*)d_in[14];
    const float* fc_w  = (const float*)d_in[15];
    const float* fc_b  = (const float*)d_in[16];
    const float* h0    = (const float*)d_in[17];
    const float* c0    = (const float*)d_in[18];

    // workspace layout (~17 MB); xb/h1 have N+16 rows (row ZROW = 0)
    const size_t NR = (size_t)N_NODES + 16;
    int* bincnt = (int*)d_ws;                                 // 256 ints
    unsigned* binbuf = (unsigned*)(bincnt + 256);             // BINS*BCAP
    unsigned short* xb = (unsigned short*)(binbuf + (size_t)BINS * BCAP);
    unsigned short* h1 = xb + NR * D;                         // [NR,64] mlp1 out
    unsigned short* wb = h1 + NR * D;                         // 4 x [64,64] bf16
    float* psum = (float*)(wb + 4 * D * D);                   // [B,64]
    float* cnts = psum + B * D;                               // [B]

    float* out_probs = (float*)d_out;
    float* out_h1    = out_probs + B * OUT;
    float* out_c1    = out_h1 + B * HL;

    // ---- bincnt zero (1 KB) + prologue (binA || cvt || init) ----
    hipMemsetAsync(bincnt, 0, 256 * sizeof(int), stream);
    pro_kernel<<<AB + CB + 1, 256, 0, stream>>>(
        ei, bincnt, binbuf, x, xb, w1, w2, w3, w4, wb, h1, psum, cnts);

    // ---- layer 1 (fused bucket-build + gather + MLP), 512 threads ----
    gmlp_kernel<<<MB, 512, 0, stream>>>(xb, bincnt, binbuf,
                                        wb, b1, wb + 4096, b2, h1);

    // ---- layer 2 (fused bucket-build + gather + MLP + pool), 512 thr ----
    g2mlp_pool_kernel<<<MB, 512, 0, stream>>>(h1, bincnt, binbuf,
                                              wb + 8192, b3, wb + 12288, b4,
                                              batch, psum, cnts);

    // ---- head ----
    head_kernel<<<B, 512, 0, stream>>>(psum, cnts, w_ih, w_hh, b_ih, b_hh,
                                       fc_w, fc_b, h0, c0,
                                       out_probs, out_h1, out_c1);
}

// Round 7
// 208.322 us; speedup vs baseline: 1.1172x; 1.0050x over previous
//
#include <hip/hip_runtime.h>
#include <hip/hip_bf16.h>

#define N_NODES 50000
#define N_EDGES 800000
#define D 64
#define B 64
#define HL 128
#define OUT 32

#define CAP 64          // max in-degree capacity (Poisson(16): P(>=64) ~ 1e-18)
#define STP 72          // LDS transform tile row stride (ushorts)
#define ZROW N_NODES    // sentinel index (u16-safe: 50000 < 65536)

#define BINS 196        // ceil(N_NODES/256): coarse bins of 256 nodes (dst>>8)
#define EPB 2048        // edges per block in binA (R3-proven)
#define LCAP 48         // per-(block,bin) LDS staging cap
#define BCAP 4608       // per-bin global region cap (mean 4082)

#define AB 391          // binA blocks
#define CB 3125         // cvt blocks (N*D/4/256)
#define MB 782          // mlp blocks (64 nodes each)
#define SWGRID 800      // swizzled layer grid: 25 groups x 4 members x 8 XCDs

typedef __attribute__((ext_vector_type(8))) short          short8;
typedef __attribute__((ext_vector_type(8))) unsigned short ushort8_t;
typedef __attribute__((ext_vector_type(4))) float          floatx4;

// bf16 helpers (RNE pack, cheap unpack)
__device__ __forceinline__ unsigned short f2bf(float f)
{
    unsigned u = __float_as_uint(f);
    u = (u + 0x7FFFu + ((u >> 16) & 1u)) >> 16;
    return (unsigned short)u;
}
__device__ __forceinline__ float bfLO(unsigned u) { return __uint_as_float(u << 16); }
__device__ __forceinline__ float bfHI(unsigned u) { return __uint_as_float(u & 0xffff0000u); }

// XCD-affine de-swizzle: launch index l -> original block o such that the 4
// blocks of one bin (o = 4g..4g+3) share l%8 (same XCD under round-robin
// dispatch) -> the bin's binbuf region is scanned from one XCD's L2.
// Bijection [0,800) -> [0,800): g = (l>>5)*8 + (l&7), o = g*4 + ((l>>3)&3).
__device__ __forceinline__ int deswizzle_block(int l)
{
    int g = ((l >> 5) << 3) | (l & 7);
    return (g << 2) | ((l >> 3) & 3);
}

// ---------------------------------------------------------------------------
// Prologue, block-range roles (independent work in one dispatch):
//   [0, AB)        : binA — bin edges by dst>>8 via LDS staging (2048 e/blk)
//   [AB, AB+CB)    : cvt x -> bf16 xb (first 64 also convert MLP weights)
//   AB+CB          : init — sentinel zero rows + psum/cnts zero
// bincnt is zeroed by a prior 1KB memset.
// ---------------------------------------------------------------------------
__global__ __launch_bounds__(256) void pro_kernel(
    const int*   __restrict__ ei,
    int*         __restrict__ bincnt,
    unsigned*    __restrict__ binbuf,
    const float* __restrict__ x, unsigned short* __restrict__ xb,
    const float* __restrict__ w1, const float* __restrict__ w2,
    const float* __restrict__ w3, const float* __restrict__ w4,
    unsigned short* __restrict__ wb,
    unsigned short* __restrict__ h1,
    float*       __restrict__ psum,
    float*       __restrict__ cnts)
{
    __shared__ int      lcnt[BINS];
    __shared__ int      gbase[BINS];
    __shared__ unsigned lbuf[BINS * LCAP];   // 36.8 KB

    int t = threadIdx.x;

    if (blockIdx.x < AB) {
        // ---------------- binA ----------------
        if (t < BINS) lcnt[t] = 0;
        __syncthreads();

        int base = blockIdx.x * EPB;
#pragma unroll
        for (int i = 0; i < EPB / 256; ++i) {
            int e = base + i * 256 + t;
            if (e < N_EDGES) {
                int s = ei[e];
                int d = ei[N_EDGES + e];
                int bin = d >> 8;
                unsigned pk = (unsigned)s | ((unsigned)(d & 255) << 16);
                int p = atomicAdd(&lcnt[bin], 1);
                if (p < LCAP) {
                    lbuf[bin * LCAP + p] = pk;
                } else {                          // statistically never
                    int q = atomicAdd(&bincnt[bin], 1);
                    if (q < BCAP) binbuf[bin * BCAP + q] = pk;
                }
            }
        }
        __syncthreads();

        if (t < BINS) {
            int m = lcnt[t]; m = (m < LCAP) ? m : LCAP;
            gbase[t] = (m > 0) ? atomicAdd(&bincnt[t], m) : 0;
        }
        __syncthreads();

        int wv = t >> 6, lane = t & 63;
        for (int b = wv; b < BINS; b += 4) {
            int m = lcnt[b]; m = (m < LCAP) ? m : LCAP;
            int gb = gbase[b];
            for (int j = lane; j < m; j += 64)
                if (gb + j < BCAP) binbuf[b * BCAP + gb + j] = lbuf[b * LCAP + j];
        }
    } else if (blockIdx.x < AB + CB) {
        // ---------------- cvt ----------------
        int cb = blockIdx.x - AB;
        int i = cb * 256 + t;                    // i < N*D/4
        const float4 v = reinterpret_cast<const float4*>(x)[i];
        ushort4 o;
        o.x = f2bf(v.x); o.y = f2bf(v.y); o.z = f2bf(v.z); o.w = f2bf(v.w);
        reinterpret_cast<ushort4*>(xb)[i] = o;

        if (cb < 64) {                           // 64*256 = 4*4096 weights
            int j = cb * 256 + t;
            int m = j >> 12, off = j & 4095;
            const float* src = (m == 0) ? w1 : (m == 1) ? w2 : (m == 2) ? w3 : w4;
            wb[j] = f2bf(src[off]);
        }
    } else {
        // ---------------- init ----------------
        if (t < D) {                             // sentinel zero rows
            xb[(size_t)ZROW * D + t] = 0;
            h1[(size_t)ZROW * D + t] = 0;
        }
#pragma unroll
        for (int k = 0; k < 16; ++k)             // psum[B*64] = 0
            psum[t * 16 + k] = 0.0f;
        if (t < B) cnts[t] = 0.0f;
    }
}

// ---------------------------------------------------------------------------
// Per-block LDS bucket build (256 threads): the block's 64 nodes are one
// quarter of one 256-node bin. Scan the bin's packed-edge region, keep
// entries whose dlow falls in our quarter. Rows pre-filled with ZROW ->
// branchless gather. Must be called by ALL 256 threads (has barriers).
// ---------------------------------------------------------------------------
__device__ __forceinline__ void build_bucket64(
    const int*      __restrict__ bincnt,
    const unsigned* __restrict__ binbuf,
    unsigned short* lbkt,     // [64*CAP + 16] LDS
    int*            lc,       // [64] LDS
    int bn0, int t)
{
    {
        ushort8_t fill = {ZROW, ZROW, ZROW, ZROW, ZROW, ZROW, ZROW, ZROW};
        reinterpret_cast<ushort8_t*>(lbkt)[t]       = fill;
        reinterpret_cast<ushort8_t*>(lbkt)[t + 256] = fill;
    }
    if (t < 64) lc[t] = 0;
    __syncthreads();

    const int bin = bn0 >> 8;
    const int q   = (bn0 >> 6) & 3;              // quarter within the bin
    int m = bincnt[bin]; m = (m < BCAP) ? m : BCAP;
    const unsigned* src = binbuf + bin * BCAP;
    for (int j = t; j < m; j += 256) {
        unsigned pk = src[j];
        int dlow = (pk >> 16) & 255;
        if ((dlow >> 6) == q) {
            int r = dlow & 63;
            int p = atomicAdd(&lc[r], 1);
            if (p < CAP) lbkt[r * CAP + p] = (unsigned short)(pk & 0xFFFFu);
        }
    }
    __syncthreads();
}

// ---------------------------------------------------------------------------
// Gather (R3 champion b-outer form): wave's 16-node tile -> LDS transform
// tile. Group g = lane>>4 owns node bn0+wv*16+b*4+g (b=0..3); lane c =
// lane&15 owns dims 4c..4c+3 (uint2 = 8 B/lane). Round count per b = wave
// max of ceil(deg/8); overshoot rounds read ZROW-padded bucket entries ->
// L1-hot sentinel zero row. Software-pipelined index loads.
// ---------------------------------------------------------------------------
__device__ __forceinline__ void gather16_bf16(
    const unsigned short* __restrict__ feat,
    const unsigned short* lbkt,          // [64*CAP] LDS (+pad)
    const int*            lc,            // [64] LDS
    unsigned short*       stw,           // wave's LDS tile, 16 rows x STP
    int bn0, int wv, int lane)
{
    const int g = lane >> 4;
    const int c = lane & 15;

#pragma unroll
    for (int b = 0; b < 4; ++b) {
        const int rloc = wv * 16 + b * 4 + g;
        const int node = bn0 + rloc;
        int deg = lc[rloc];
        deg = (deg < CAP) ? deg : CAP;
        int m = (deg + 7) >> 3;
        {   // wave-max over the 4 groups
            int t1 = __shfl_xor(m, 16); m = (t1 > m) ? t1 : m;
            int t2 = __shfl_xor(m, 32); m = (t2 > m) ? t2 : m;
        }

        const unsigned short* bkt = lbkt + rloc * CAP;

        // self row
        uint2 u = *reinterpret_cast<const uint2*>(feat + (size_t)node * D + 4 * c);
        float a0 = bfLO(u.x), a1 = bfHI(u.x);
        float a2 = bfLO(u.y), a3 = bfHI(u.y);

        ushort8_t idx = *reinterpret_cast<const ushort8_t*>(bkt);
        for (int r = 0; r < m; ++r) {
            ushort8_t nxt = *reinterpret_cast<const ushort8_t*>(bkt + (r + 1) * 8);
#pragma unroll
            for (int j = 0; j < 8; ++j) {
                uint2 v = *reinterpret_cast<const uint2*>(
                    feat + (size_t)idx[j] * D + 4 * c);
                a0 += bfLO(v.x); a1 += bfHI(v.x);
                a2 += bfLO(v.y); a3 += bfHI(v.y);
            }
            idx = nxt;
        }

        uint2 o;
        o.x = (unsigned)f2bf(a0) | ((unsigned)f2bf(a1) << 16);
        o.y = (unsigned)f2bf(a2) | ((unsigned)f2bf(a3) << 16);
        *reinterpret_cast<uint2*>(stw + (b * 4 + g) * STP + 4 * c) = o;
    }
}

// ---------------------------------------------------------------------------
// Fused bucket-build + gather + MLP layer 1 via MFMA (m89/m91 layouts).
// ---------------------------------------------------------------------------
__global__ __launch_bounds__(256) void gmlp_kernel(
    const unsigned short* __restrict__ feat,   // xb (bf16 rows, ZROW valid)
    const int*            __restrict__ bincnt,
    const unsigned*       __restrict__ binbuf,
    const unsigned short* __restrict__ wAb,
    const float*          __restrict__ bA,
    const unsigned short* __restrict__ wBb,
    const float*          __restrict__ bB,
    unsigned short*       __restrict__ outp)
{
    __shared__ int lc[64];
    __shared__ __align__(16) unsigned short lbkt[64 * CAP + 16];  // 8.2 KB
    __shared__ __align__(16) unsigned short st[4][16 * STP];      // 9.2 KB

    const int o = deswizzle_block(blockIdx.x);
    if (o >= MB) return;                         // padded grid: exit whole block

    const int t    = threadIdx.x;
    const int wv   = t >> 6;
    const int lane = t & 63;
    const int quad = lane >> 4;
    const int col  = lane & 15;

    const int bn0 = o * 64;
    const int n0  = bn0 + wv * 16;

    build_bucket64(bincnt, binbuf, lbkt, lc, bn0, t);

    if (n0 >= N_NODES) return;                   // after barriers: safe

    float bAl[4], bBl[4];
#pragma unroll
    for (int tt = 0; tt < 4; ++tt) {
        bAl[tt] = bA[tt * 16 + col];
        bBl[tt] = bB[tt * 16 + col];
    }

    short8 WA[4][2], WB[4][2];
#pragma unroll
    for (int tt = 0; tt < 4; ++tt)
#pragma unroll
        for (int k = 0; k < 2; ++k) {
            WA[tt][k] = *reinterpret_cast<const short8*>(
                wAb + (tt * 16 + col) * D + k * 32 + quad * 8);
            WB[tt][k] = *reinterpret_cast<const short8*>(
                wBb + (tt * 16 + col) * D + k * 32 + quad * 8);
        }

    unsigned short* stw = &st[wv][0];

    gather16_bf16(feat, lbkt, lc, stw, bn0, wv, lane);

    short8 A0 = *reinterpret_cast<const short8*>(stw + col * STP + 0 * 32 + quad * 8);
    short8 A1 = *reinterpret_cast<const short8*>(stw + col * STP + 1 * 32 + quad * 8);

#pragma unroll
    for (int tt = 0; tt < 4; ++tt) {
        floatx4 c = {0.0f, 0.0f, 0.0f, 0.0f};
        c = __builtin_amdgcn_mfma_f32_16x16x32_bf16(A0, WA[tt][0], c, 0, 0, 0);
        c = __builtin_amdgcn_mfma_f32_16x16x32_bf16(A1, WA[tt][1], c, 0, 0, 0);
#pragma unroll
        for (int r = 0; r < 4; ++r) {
            float v = fmaxf(c[r] + bAl[tt], 0.0f);
            stw[(quad * 4 + r) * STP + tt * 16 + col] = f2bf(v);
        }
    }

    short8 T0 = *reinterpret_cast<const short8*>(stw + col * STP + 0 * 32 + quad * 8);
    short8 T1 = *reinterpret_cast<const short8*>(stw + col * STP + 1 * 32 + quad * 8);

#pragma unroll
    for (int tt = 0; tt < 4; ++tt) {
        floatx4 c = {0.0f, 0.0f, 0.0f, 0.0f};
        c = __builtin_amdgcn_mfma_f32_16x16x32_bf16(T0, WB[tt][0], c, 0, 0, 0);
        c = __builtin_amdgcn_mfma_f32_16x16x32_bf16(T1, WB[tt][1], c, 0, 0, 0);
#pragma unroll
        for (int r = 0; r < 4; ++r) {
            float v = fmaxf(c[r] + bBl[tt], 0.0f);
            outp[(size_t)(n0 + quad * 4 + r) * D + tt * 16 + col] = f2bf(v);
        }
    }
}

// ---------------------------------------------------------------------------
// Fused bucket-build + gather + MLP layer 2 + mean-pool numerator +
// per-graph node counts (for the head's mean).
// ---------------------------------------------------------------------------
__global__ __launch_bounds__(256) void g2mlp_pool_kernel(
    const unsigned short* __restrict__ feat,   // h1 (layer-1 output, bf16)
    const int*            __restrict__ bincnt,
    const unsigned*       __restrict__ binbuf,
    const unsigned short* __restrict__ wAb,
    const float*          __restrict__ bA,
    const unsigned short* __restrict__ wBb,
    const float*          __restrict__ bB,
    const int*            __restrict__ batch,  // [N] sorted
    float*                __restrict__ psum,   // [B,64] zero-initialized
    float*                __restrict__ cnts)   // [B] zero-initialized
{
    __shared__ int lc[64];
    __shared__ __align__(16) unsigned short lbkt[64 * CAP + 16];
    __shared__ __align__(16) unsigned short st[4][16 * STP];
    __shared__ float pt[64][D + 1];            // block's 64-node output tile
    __shared__ int   sbatch[64];

    const int o = deswizzle_block(blockIdx.x);
    if (o >= MB) return;                         // padded grid: exit whole block

    const int t    = threadIdx.x;
    const int wv   = t >> 6;
    const int lane = t & 63;
    const int quad = lane >> 4;
    const int col  = lane & 15;

    const int bn0 = o * 64;
    const int n0  = bn0 + wv * 16;
    const bool active = (n0 < N_NODES);

    if (t < 64) {
        int n = bn0 + t;
        sbatch[t] = (n < N_NODES) ? batch[n] : -1;
    }
    // (sbatch covered by build_bucket64's first __syncthreads)

    build_bucket64(bincnt, binbuf, lbkt, lc, bn0, t);

    if (active) {
        float bAl[4], bBl[4];
#pragma unroll
        for (int tt = 0; tt < 4; ++tt) {
            bAl[tt] = bA[tt * 16 + col];
            bBl[tt] = bB[tt * 16 + col];
        }

        short8 WA[4][2], WB[4][2];
#pragma unroll
        for (int tt = 0; tt < 4; ++tt)
#pragma unroll
            for (int k = 0; k < 2; ++k) {
                WA[tt][k] = *reinterpret_cast<const short8*>(
                    wAb + (tt * 16 + col) * D + k * 32 + quad * 8);
                WB[tt][k] = *reinterpret_cast<const short8*>(
                    wBb + (tt * 16 + col) * D + k * 32 + quad * 8);
            }

        unsigned short* stw = &st[wv][0];

        gather16_bf16(feat, lbkt, lc, stw, bn0, wv, lane);

        short8 A0 = *reinterpret_cast<const short8*>(stw + col * STP + 0 * 32 + quad * 8);
        short8 A1 = *reinterpret_cast<const short8*>(stw + col * STP + 1 * 32 + quad * 8);

#pragma unroll
        for (int tt = 0; tt < 4; ++tt) {
            floatx4 c = {0.0f, 0.0f, 0.0f, 0.0f};
            c = __builtin_amdgcn_mfma_f32_16x16x32_bf16(A0, WA[tt][0], c, 0, 0, 0);
            c = __builtin_amdgcn_mfma_f32_16x16x32_bf16(A1, WA[tt][1], c, 0, 0, 0);
#pragma unroll
            for (int r = 0; r < 4; ++r) {
                float v = fmaxf(c[r] + bAl[tt], 0.0f);
                stw[(quad * 4 + r) * STP + tt * 16 + col] = f2bf(v);
            }
        }

        short8 T0 = *reinterpret_cast<const short8*>(stw + col * STP + 0 * 32 + quad * 8);
        short8 T1 = *reinterpret_cast<const short8*>(stw + col * STP + 1 * 32 + quad * 8);

#pragma unroll
        for (int tt = 0; tt < 4; ++tt) {
            floatx4 c = {0.0f, 0.0f, 0.0f, 0.0f};
            c = __builtin_amdgcn_mfma_f32_16x16x32_bf16(T0, WB[tt][0], c, 0, 0, 0);
            c = __builtin_amdgcn_mfma_f32_16x16x32_bf16(T1, WB[tt][1], c, 0, 0, 0);
#pragma unroll
            for (int r = 0; r < 4; ++r) {
                float v = fmaxf(c[r] + bBl[tt], 0.0f);
                pt[wv * 16 + quad * 4 + r][tt * 16 + col] = v;
            }
        }
    } else {
        // inactive wave: zero its tile rows so the reduce sees zeros
        for (int c2 = 0; c2 < 4; ++c2)
#pragma unroll
            for (int r = 0; r < 4; ++r)
                pt[wv * 16 + quad * 4 + r][c2 * 16 + col] = 0.0f;
    }
    __syncthreads();

    // segmented reduce: thread (q,d) sums rows q*16..q*16+15 of dim d,
    // flushing one atomicAdd per graph run; d==0 thread also counts rows.
    int q = t >> 6;
    int d = t & 63;
    float acc = 0.0f;
    int   len = 0;
    int curg = sbatch[q * 16];
#pragma unroll
    for (int r = 0; r < 16; ++r) {
        int row = q * 16 + r;
        int g2 = sbatch[row];
        float v = pt[row][d];
        if (g2 != curg) {
            if (curg >= 0) {
                atomicAdd(&psum[curg * D + d], acc);
                if (d == 0) atomicAdd(&cnts[curg], (float)len);
            }
            acc = 0.0f; len = 0;
            curg = g2;
        }
        acc += v;
        len += 1;
    }
    if (curg >= 0) {
        atomicAdd(&psum[curg * D + d], acc);
        if (d == 0) atomicAdd(&cnts[curg], (float)len);
    }
}

// ---------------------------------------------------------------------------
// Head: mean from psum + cnts, single-step LSTM + FC + softmax.
// ---------------------------------------------------------------------------
__device__ __forceinline__ float sigmoidf_(float x) { return 1.0f / (1.0f + expf(-x)); }

__global__ __launch_bounds__(512) void head_kernel(
    const float* __restrict__ psum,   // [B,64] pooled sums
    const float* __restrict__ cnts,   // [B] node counts
    const float* __restrict__ w_ih,
    const float* __restrict__ w_hh,
    const float* __restrict__ b_ih,
    const float* __restrict__ b_hh,
    const float* __restrict__ fc_w,
    const float* __restrict__ fc_b,
    const float* __restrict__ h0,
    const float* __restrict__ c0,
    float*       __restrict__ out_probs,
    float*       __restrict__ out_h1,
    float*       __restrict__ out_c1)
{
    int b = blockIdx.x;
    int j = threadIdx.x;

    __shared__ float sp[D];
    __shared__ float sh[HL];
    __shared__ float gates[4 * HL];
    __shared__ float sh1[HL];
    __shared__ float slog[OUT];

    if (j < D) {
        sp[j] = psum[b * D + j] / fmaxf(cnts[b], 1.0f);
    } else if (j < D + HL) {
        sh[j - D] = h0[b * HL + (j - D)];
    }
    __syncthreads();

    {
        float acc = b_ih[j] + b_hh[j];
#pragma unroll
        for (int k = 0; k < D; ++k)  acc = fmaf(sp[k], w_ih[j * D + k], acc);
#pragma unroll
        for (int k = 0; k < HL; ++k) acc = fmaf(sh[k], w_hh[j * HL + k], acc);
        gates[j] = acc;
    }
    __syncthreads();

    if (j < HL) {
        float ig = gates[j];
        float fg = gates[HL + j];
        float gg = gates[2 * HL + j];
        float og = gates[3 * HL + j];
        float c  = sigmoidf_(fg) * c0[b * HL + j] + sigmoidf_(ig) * tanhf(gg);
        float hv = sigmoidf_(og) * tanhf(c);
        out_c1[b * HL + j] = c;
        out_h1[b * HL + j] = hv;
        sh1[j] = hv;
    }
    __syncthreads();

    if (j < OUT) {
        float a = fc_b[j];
#pragma unroll
        for (int k = 0; k < HL; ++k) a = fmaf(sh1[k], fc_w[j * HL + k], a);
        slog[j] = a;
    }
    __syncthreads();

    if (j < OUT) {
        float m = -1e30f;
#pragma unroll
        for (int k = 0; k < OUT; ++k) m = fmaxf(m, slog[k]);
        float s = 0.0f;
#pragma unroll
        for (int k = 0; k < OUT; ++k) s += expf(slog[k] - m);
        out_probs[b * OUT + j] = expf(slog[j] - m) / s;
    }
}

// ---------------------------------------------------------------------------
extern "C" void kernel_launch(void* const* d_in, const int* in_sizes, int n_in,
                              void* d_out, int out_size, void* d_ws, size_t ws_size,
                              hipStream_t stream)
{
    const float* x     = (const float*)d_in[0];
    const int*   ei    = (const int*)  d_in[1];
    const int*   batch = (const int*)  d_in[2];
    const float* w1    = (const float*)d_in[3];
    const float* b1    = (const float*)d_in[4];
    const float* w2    = (const float*)d_in[5];
    const float* b2    = (const float*)d_in[6];
    const float* w3    = (const float*)d_in[7];
    const float* b3    = (const float*)d_in[8];
    const float* w4    = (const float*)d_in[9];
    const float* b4    = (const float*)d_in[10];
    const float* w_ih  = (const float*)d_in[11];
    const float* w_hh  = (const float*)d_in[12];
    const float* b_ih  = (const float*)d_in[13];
    const float* b_hh  = (const float*)d_in[14];
    const float* fc_w  = (const float*)d_in[15];
    const float* fc_b  = (const float*)d_in[16];
    const float* h0    = (const float*)d_in[17];
    const float* c0    = (const float*)d_in[18];

    // workspace layout (~17 MB); xb/h1 have N+16 rows (row ZROW = 0)
    const size_t NR = (size_t)N_NODES + 16;
    int* bincnt = (int*)d_ws;                                 // 256 ints
    unsigned* binbuf = (unsigned*)(bincnt + 256);             // BINS*BCAP
    unsigned short* xb = (unsigned short*)(binbuf + (size_t)BINS * BCAP);
    unsigned short* h1 = xb + NR * D;                         // [NR,64] mlp1 out
    unsigned short* wb = h1 + NR * D;                         // 4 x [64,64] bf16
    float* psum = (float*)(wb + 4 * D * D);                   // [B,64]
    float* cnts = psum + B * D;                               // [B]

    float* out_probs = (float*)d_out;
    float* out_h1    = out_probs + B * OUT;
    float* out_c1    = out_h1 + B * HL;

    // ---- bincnt zero (1 KB) + prologue (binA || cvt || init) ----
    hipMemsetAsync(bincnt, 0, 256 * sizeof(int), stream);
    pro_kernel<<<AB + CB + 1, 256, 0, stream>>>(
        ei, bincnt, binbuf, x, xb, w1, w2, w3, w4, wb, h1, psum, cnts);

    // ---- layer 1 (fused bucket-build + gather + MLP), XCD-affine grid ----
    gmlp_kernel<<<SWGRID, 256, 0, stream>>>(xb, bincnt, binbuf,
                                            wb, b1, wb + 4096, b2, h1);

    // ---- layer 2 (fused bucket-build + gather + MLP + pool) ----
    g2mlp_pool_kernel<<<SWGRID, 256, 0, stream>>>(h1, bincnt, binbuf,
                                                  wb + 8192, b3, wb + 12288, b4,
                                                  batch, psum, cnts);

    // ---- head ----
    head_kernel<<<B, 512, 0, stream>>>(psum, cnts, w_ih, w_hh, b_ih, b_hh,
                                       fc_w, fc_b, h0, c0,
                                       out_probs, out_h1, out_c1);
}

// Round 8
// 199.025 us; speedup vs baseline: 1.1693x; 1.0467x over previous
//
#include <hip/hip_runtime.h>
#include <hip/hip_bf16.h>

#define N_NODES 50000
#define N_EDGES 800000
#define D 64
#define B 64
#define HL 128
#define OUT 32

#define CAP 64          // max in-degree capacity (Poisson(16): P(>=64) ~ 1e-18)
#define STP 72          // LDS transform tile row stride (ushorts)
#define ZROW N_NODES    // sentinel index (u16-safe: 50000 < 65536)

#define BINS 196        // ceil(N_NODES/256): coarse bins of 256 nodes (dst>>8)
#define EPB 2048        // edges per block in binA
#define LCAP 48         // per-(block,bin) LDS staging cap
#define BCAP 4608       // per-bin global region cap (mean 4082)

#define AB 391          // binA blocks
#define CB 3125         // cvt blocks (N*D/4/256)
#define MB 782          // mlp blocks (64 nodes each)

typedef __attribute__((ext_vector_type(8))) short          short8;
typedef __attribute__((ext_vector_type(8))) unsigned short ushort8_t;
typedef __attribute__((ext_vector_type(4))) float          floatx4;

// bf16 helpers (RNE pack, cheap unpack)
__device__ __forceinline__ unsigned short f2bf(float f)
{
    unsigned u = __float_as_uint(f);
    u = (u + 0x7FFFu + ((u >> 16) & 1u)) >> 16;
    return (unsigned short)u;
}
__device__ __forceinline__ float bfLO(unsigned u) { return __uint_as_float(u << 16); }
__device__ __forceinline__ float bfHI(unsigned u) { return __uint_as_float(u & 0xffff0000u); }

// ---------------------------------------------------------------------------
// Fused prologue, block-range roles (independent work overlaps in 1 dispatch):
//   [0, AB)        : binA — bin edges by dst>>8 via LDS staging
//   [AB, AB+CB)    : cvt x -> bf16 (first 64 also convert MLP weights)
//   AB+CB          : init — sentinel zero rows + psum zero
// bincnt is zeroed by a prior 1KB memset.
// ---------------------------------------------------------------------------
__global__ __launch_bounds__(256) void fused_pro_kernel(
    const int*   __restrict__ ei,
    int*         __restrict__ bincnt,
    unsigned*    __restrict__ binbuf,
    const float* __restrict__ x, unsigned short* __restrict__ xb,
    const float* __restrict__ w1, const float* __restrict__ w2,
    const float* __restrict__ w3, const float* __restrict__ w4,
    unsigned short* __restrict__ wb,
    unsigned short* __restrict__ h1,
    float*       __restrict__ psum)
{
    __shared__ int      lcnt[BINS];
    __shared__ int      gbase[BINS];
    __shared__ unsigned lbuf[BINS * LCAP];   // 37.6 KB

    int t = threadIdx.x;

    if (blockIdx.x < AB) {
        // ---------------- binA ----------------
        if (t < BINS) lcnt[t] = 0;
        __syncthreads();

        int base = blockIdx.x * EPB;
#pragma unroll
        for (int i = 0; i < EPB / 256; ++i) {
            int e = base + i * 256 + t;
            if (e < N_EDGES) {
                int s = ei[e];
                int d = ei[N_EDGES + e];
                int bin = d >> 8;
                unsigned pk = (unsigned)s | ((unsigned)(d & 255) << 16);
                int p = atomicAdd(&lcnt[bin], 1);
                if (p < LCAP) {
                    lbuf[bin * LCAP + p] = pk;
                } else {                          // statistically never
                    int q = atomicAdd(&bincnt[bin], 1);
                    if (q < BCAP) binbuf[bin * BCAP + q] = pk;
                }
            }
        }
        __syncthreads();

        if (t < BINS) {
            int m = lcnt[t]; m = (m < LCAP) ? m : LCAP;
            gbase[t] = (m > 0) ? atomicAdd(&bincnt[t], m) : 0;
        }
        __syncthreads();

        int wv = t >> 6, lane = t & 63;
        for (int b = wv; b < BINS; b += 4) {
            int m = lcnt[b]; m = (m < LCAP) ? m : LCAP;
            int gb = gbase[b];
            for (int j = lane; j < m; j += 64)
                if (gb + j < BCAP) binbuf[b * BCAP + gb + j] = lbuf[b * LCAP + j];
        }
    } else if (blockIdx.x < AB + CB) {
        // ---------------- cvt ----------------
        int cb = blockIdx.x - AB;
        int i = cb * 256 + t;                    // i < N*D/4
        const float4 v = reinterpret_cast<const float4*>(x)[i];
        ushort4 o;
        o.x = f2bf(v.x); o.y = f2bf(v.y); o.z = f2bf(v.z); o.w = f2bf(v.w);
        reinterpret_cast<ushort4*>(xb)[i] = o;

        if (cb < 64) {                           // 64*256 = 4*4096
            int j = cb * 256 + t;
            int m = j >> 12, off = j & 4095;
            const float* src = (m == 0) ? w1 : (m == 1) ? w2 : (m == 2) ? w3 : w4;
            wb[j] = f2bf(src[off]);
        }
    } else {
        // ---------------- init ----------------
        if (t < D) {                             // sentinel zero rows
            xb[(size_t)ZROW * D + t] = 0;
            h1[(size_t)ZROW * D + t] = 0;
        }
#pragma unroll
        for (int k = 0; k < 16; ++k)             // psum[B*64] = 0
            psum[t * 16 + k] = 0.0f;
    }
}

// ---------------------------------------------------------------------------
// Per-block LDS bucket build: the block's 64 nodes are one quarter of one
// 256-node bin. Scan the bin's packed-edge region once, keep entries whose
// dlow falls in our quarter. Rows pre-filled with ZROW -> branchless gather.
// Must be called by ALL 256 threads (contains __syncthreads).
// ---------------------------------------------------------------------------
__device__ __forceinline__ void build_bucket64(
    const int*      __restrict__ bincnt,
    const unsigned* __restrict__ binbuf,
    unsigned short* lbkt,     // [64*CAP + 16] LDS
    int*            lc,       // [64] LDS
    int bn0, int t)
{
    {
        ushort8_t fill = {ZROW, ZROW, ZROW, ZROW, ZROW, ZROW, ZROW, ZROW};
        reinterpret_cast<ushort8_t*>(lbkt)[t]       = fill;
        reinterpret_cast<ushort8_t*>(lbkt)[t + 256] = fill;
    }
    if (t < 64) lc[t] = 0;
    __syncthreads();

    const int bin = bn0 >> 8;
    const int q   = (bn0 >> 6) & 3;              // quarter within the bin
    int m = bincnt[bin]; m = (m < BCAP) ? m : BCAP;
    const unsigned* src = binbuf + bin * BCAP;
    for (int j = t; j < m; j += 256) {
        unsigned pk = src[j];
        int dlow = (pk >> 16) & 255;
        if ((dlow >> 6) == q) {
            int r = dlow & 63;
            int p = atomicAdd(&lc[r], 1);
            if (p < CAP) lbkt[r * CAP + p] = (unsigned short)(pk & 0xFFFFu);
        }
    }
    __syncthreads();
}

// ---------------------------------------------------------------------------
// Gather of a wave's 16-node tile into its LDS transform tile, indices from
// the block-local LDS bucket. Wave processes 4 nodes at a time: group
// g = lane>>4 owns node bn0+wv*16+b*4+g, lane c = lane&15 owns dims
// 4c..4c+3 (uint2 = 8 B/lane). Bucket rows ZROW-padded -> overshoot rows
// add cached zeros. Loop trip = max over the 4 groups (shfl-xor max).
// ---------------------------------------------------------------------------
__device__ __forceinline__ void gather16_lds(
    const unsigned short* __restrict__ feat,
    const unsigned short* lbkt,          // [64*CAP] LDS (+pad)
    const int*            lc,            // [64] LDS
    unsigned short*       stw,           // wave's LDS tile, 16 rows x STP
    int bn0, int wv, int lane)
{
    const int g = lane >> 4;
    const int c = lane & 15;

#pragma unroll
    for (int b = 0; b < 4; ++b) {
        const int rloc = wv * 16 + b * 4 + g;
        const int node = bn0 + rloc;
        int deg = lc[rloc];
        deg = (deg < CAP) ? deg : CAP;
        int m = (deg + 7) >> 3;
        {   // wave-max over the 4 groups
            int t1 = __shfl_xor(m, 16); m = (t1 > m) ? t1 : m;
            int t2 = __shfl_xor(m, 32); m = (t2 > m) ? t2 : m;
        }

        const unsigned short* bkt = lbkt + rloc * CAP;

        // self row
        uint2 u = *reinterpret_cast<const uint2*>(feat + (size_t)node * D + 4 * c);
        float a0 = bfLO(u.x), a1 = bfHI(u.x);
        float a2 = bfLO(u.y), a3 = bfHI(u.y);

        // idx reads are LDS (group-uniform address -> broadcast, no conflict)
        ushort8_t idx = *reinterpret_cast<const ushort8_t*>(bkt);
        for (int r = 0; r < m; ++r) {
            ushort8_t nxt = *reinterpret_cast<const ushort8_t*>(bkt + (r + 1) * 8);
#pragma unroll
            for (int j = 0; j < 8; ++j) {
                uint2 v = *reinterpret_cast<const uint2*>(
                    feat + (size_t)idx[j] * D + 4 * c);
                a0 += bfLO(v.x); a1 += bfHI(v.x);
                a2 += bfLO(v.y); a3 += bfHI(v.y);
            }
            idx = nxt;
        }

        uint2 o;
        o.x = (unsigned)f2bf(a0) | ((unsigned)f2bf(a1) << 16);
        o.y = (unsigned)f2bf(a2) | ((unsigned)f2bf(a3) << 16);
        *reinterpret_cast<uint2*>(stw + (b * 4 + g) * STP + 4 * c) = o;
    }
}

// ---------------------------------------------------------------------------
// Fused bucket-build + gather + MLP layer 1 via MFMA (m89/m91 layouts).
// ---------------------------------------------------------------------------
__global__ __launch_bounds__(256) void gmlp_kernel(
    const unsigned short* __restrict__ feat,   // node features (bf16 rows)
    const int*            __restrict__ bincnt,
    const unsigned*       __restrict__ binbuf,
    const unsigned short* __restrict__ wAb,
    const float*          __restrict__ bA,
    const unsigned short* __restrict__ wBb,
    const float*          __restrict__ bB,
    unsigned short*       __restrict__ outp)
{
    __shared__ int lc[64];
    __shared__ __align__(16) unsigned short lbkt[64 * CAP + 16];  // 8.2 KB
    __shared__ __align__(16) unsigned short st[4][16 * STP];      // 9.2 KB

    const int t    = threadIdx.x;
    const int wv   = t >> 6;
    const int lane = t & 63;
    const int quad = lane >> 4;
    const int col  = lane & 15;

    const int bn0 = blockIdx.x * 64;
    const int n0  = bn0 + wv * 16;

    build_bucket64(bincnt, binbuf, lbkt, lc, bn0, t);

    if (n0 >= N_NODES) return;                   // after barriers: safe

    float bAl[4], bBl[4];
#pragma unroll
    for (int tt = 0; tt < 4; ++tt) {
        bAl[tt] = bA[tt * 16 + col];
        bBl[tt] = bB[tt * 16 + col];
    }

    short8 WA[4][2], WB[4][2];
#pragma unroll
    for (int tt = 0; tt < 4; ++tt)
#pragma unroll
        for (int k = 0; k < 2; ++k) {
            WA[tt][k] = *reinterpret_cast<const short8*>(
                wAb + (tt * 16 + col) * D + k * 32 + quad * 8);
            WB[tt][k] = *reinterpret_cast<const short8*>(
                wBb + (tt * 16 + col) * D + k * 32 + quad * 8);
        }

    unsigned short* stw = &st[wv][0];

    gather16_lds(feat, lbkt, lc, stw, bn0, wv, lane);

    short8 A0 = *reinterpret_cast<const short8*>(stw + col * STP + 0 * 32 + quad * 8);
    short8 A1 = *reinterpret_cast<const short8*>(stw + col * STP + 1 * 32 + quad * 8);

#pragma unroll
    for (int tt = 0; tt < 4; ++tt) {
        floatx4 c = {0.0f, 0.0f, 0.0f, 0.0f};
        c = __builtin_amdgcn_mfma_f32_16x16x32_bf16(A0, WA[tt][0], c, 0, 0, 0);
        c = __builtin_amdgcn_mfma_f32_16x16x32_bf16(A1, WA[tt][1], c, 0, 0, 0);
#pragma unroll
        for (int r = 0; r < 4; ++r) {
            float v = fmaxf(c[r] + bAl[tt], 0.0f);
            stw[(quad * 4 + r) * STP + tt * 16 + col] = f2bf(v);
        }
    }

    short8 T0 = *reinterpret_cast<const short8*>(stw + col * STP + 0 * 32 + quad * 8);
    short8 T1 = *reinterpret_cast<const short8*>(stw + col * STP + 1 * 32 + quad * 8);

#pragma unroll
    for (int tt = 0; tt < 4; ++tt) {
        floatx4 c = {0.0f, 0.0f, 0.0f, 0.0f};
        c = __builtin_amdgcn_mfma_f32_16x16x32_bf16(T0, WB[tt][0], c, 0, 0, 0);
        c = __builtin_amdgcn_mfma_f32_16x16x32_bf16(T1, WB[tt][1], c, 0, 0, 0);
#pragma unroll
        for (int r = 0; r < 4; ++r) {
            float v = fmaxf(c[r] + bBl[tt], 0.0f);
            outp[(size_t)(n0 + quad * 4 + r) * D + tt * 16 + col] = f2bf(v);
        }
    }
}

// ---------------------------------------------------------------------------
// Fused bucket-build + gather + MLP layer 2 + mean-pool numerator.
// ---------------------------------------------------------------------------
__global__ __launch_bounds__(256) void g2mlp_pool_kernel(
    const unsigned short* __restrict__ feat,   // h1 (layer-1 output)
    const int*            __restrict__ bincnt,
    const unsigned*       __restrict__ binbuf,
    const unsigned short* __restrict__ wAb,
    const float*          __restrict__ bA,
    const unsigned short* __restrict__ wBb,
    const float*          __restrict__ bB,
    const int*            __restrict__ batch,  // [N] sorted
    float*                __restrict__ psum)   // [B,64] zero-initialized
{
    __shared__ int lc[64];
    __shared__ __align__(16) unsigned short lbkt[64 * CAP + 16];
    __shared__ __align__(16) unsigned short st[4][16 * STP];
    __shared__ float pt[64][D + 1];            // block's 64-node output tile
    __shared__ int   sbatch[64];

    const int t    = threadIdx.x;
    const int wv   = t >> 6;
    const int lane = t & 63;
    const int quad = lane >> 4;
    const int col  = lane & 15;

    const int bn0 = blockIdx.x * 64;
    const int n0  = bn0 + wv * 16;
    const bool active = (n0 < N_NODES);

    if (t < 64) {
        int n = bn0 + t;
        sbatch[t] = (n < N_NODES) ? batch[n] : -1;
    }
    // (sbatch covered by build_bucket64's first __syncthreads)

    build_bucket64(bincnt, binbuf, lbkt, lc, bn0, t);

    if (active) {
        float bAl[4], bBl[4];
#pragma unroll
        for (int tt = 0; tt < 4; ++tt) {
            bAl[tt] = bA[tt * 16 + col];
            bBl[tt] = bB[tt * 16 + col];
        }

        short8 WA[4][2], WB[4][2];
#pragma unroll
        for (int tt = 0; tt < 4; ++tt)
#pragma unroll
            for (int k = 0; k < 2; ++k) {
                WA[tt][k] = *reinterpret_cast<const short8*>(
                    wAb + (tt * 16 + col) * D + k * 32 + quad * 8);
                WB[tt][k] = *reinterpret_cast<const short8*>(
                    wBb + (tt * 16 + col) * D + k * 32 + quad * 8);
            }

        unsigned short* stw = &st[wv][0];

        gather16_lds(feat, lbkt, lc, stw, bn0, wv, lane);

        short8 A0 = *reinterpret_cast<const short8*>(stw + col * STP + 0 * 32 + quad * 8);
        short8 A1 = *reinterpret_cast<const short8*>(stw + col * STP + 1 * 32 + quad * 8);

#pragma unroll
        for (int tt = 0; tt < 4; ++tt) {
            floatx4 c = {0.0f, 0.0f, 0.0f, 0.0f};
            c = __builtin_amdgcn_mfma_f32_16x16x32_bf16(A0, WA[tt][0], c, 0, 0, 0);
            c = __builtin_amdgcn_mfma_f32_16x16x32_bf16(A1, WA[tt][1], c, 0, 0, 0);
#pragma unroll
            for (int r = 0; r < 4; ++r) {
                float v = fmaxf(c[r] + bAl[tt], 0.0f);
                stw[(quad * 4 + r) * STP + tt * 16 + col] = f2bf(v);
            }
        }

        short8 T0 = *reinterpret_cast<const short8*>(stw + col * STP + 0 * 32 + quad * 8);
        short8 T1 = *reinterpret_cast<const short8*>(stw + col * STP + 1 * 32 + quad * 8);

#pragma unroll
        for (int tt = 0; tt < 4; ++tt) {
            floatx4 c = {0.0f, 0.0f, 0.0f, 0.0f};
            c = __builtin_amdgcn_mfma_f32_16x16x32_bf16(T0, WB[tt][0], c, 0, 0, 0);
            c = __builtin_amdgcn_mfma_f32_16x16x32_bf16(T1, WB[tt][1], c, 0, 0, 0);
#pragma unroll
            for (int r = 0; r < 4; ++r) {
                float v = fmaxf(c[r] + bBl[tt], 0.0f);
                pt[wv * 16 + quad * 4 + r][tt * 16 + col] = v;
            }
        }
    } else {
        // inactive wave: zero its tile rows so the reduce sees zeros
        for (int c2 = 0; c2 < 4; ++c2)
#pragma unroll
            for (int r = 0; r < 4; ++r)
                pt[wv * 16 + quad * 4 + r][c2 * 16 + col] = 0.0f;
    }
    __syncthreads();

    // segmented reduce: thread (q,d) sums rows q*16..q*16+15 of dim d,
    // flushing one atomicAdd per graph run (sorted batch => few runs).
    int q = t >> 6;
    int d = t & 63;
    float acc = 0.0f;
    int curg = sbatch[q * 16];
#pragma unroll
    for (int r = 0; r < 16; ++r) {
        int row = q * 16 + r;
        int g2 = sbatch[row];
        float v = pt[row][d];
        if (g2 != curg) {
            if (curg >= 0) atomicAdd(&psum[curg * D + d], acc);
            acc = 0.0f;
            curg = g2;
        }
        acc += v;
    }
    if (curg >= 0) atomicAdd(&psum[curg * D + d], acc);
}

// ---------------------------------------------------------------------------
// Head: mean from psum + counts, single-step LSTM + FC + softmax.
// ---------------------------------------------------------------------------
__device__ __forceinline__ int lower_bound_dev(const int* a, int n, int v)
{
    int lo = 0, hi = n;
    while (lo < hi) {
        int m = (lo + hi) >> 1;
        if (a[m] < v) lo = m + 1; else hi = m;
    }
    return lo;
}

__device__ __forceinline__ float sigmoidf_(float x) { return 1.0f / (1.0f + expf(-x)); }

__global__ __launch_bounds__(512) void head_kernel(
    const float* __restrict__ psum,   // [B,64] pooled sums
    const int*   __restrict__ batch,  // [N]
    const float* __restrict__ w_ih,
    const float* __restrict__ w_hh,
    const float* __restrict__ b_ih,
    const float* __restrict__ b_hh,
    const float* __restrict__ fc_w,
    const float* __restrict__ fc_b,
    const float* __restrict__ h0,
    const float* __restrict__ c0,
    float*       __restrict__ out_probs,
    float*       __restrict__ out_h1,
    float*       __restrict__ out_c1)
{
    int b = blockIdx.x;
    int j = threadIdx.x;

    __shared__ float sp[D];
    __shared__ float sh[HL];
    __shared__ float gates[4 * HL];
    __shared__ float sh1[HL];
    __shared__ float slog[OUT];

    if (j < D) {
        int start = lower_bound_dev(batch, N_NODES, b);
        int end   = lower_bound_dev(batch, N_NODES, b + 1);
        sp[j] = psum[b * D + j] / fmaxf((float)(end - start), 1.0f);
    } else if (j < D + HL) {
        sh[j - D] = h0[b * HL + (j - D)];
    }
    __syncthreads();

    {
        float acc = b_ih[j] + b_hh[j];
#pragma unroll
        for (int k = 0; k < D; ++k)  acc = fmaf(sp[k], w_ih[j * D + k], acc);
#pragma unroll
        for (int k = 0; k < HL; ++k) acc = fmaf(sh[k], w_hh[j * HL + k], acc);
        gates[j] = acc;
    }
    __syncthreads();

    if (j < HL) {
        float ig = gates[j];
        float fg = gates[HL + j];
        float gg = gates[2 * HL + j];
        float og = gates[3 * HL + j];
        float c  = sigmoidf_(fg) * c0[b * HL + j] + sigmoidf_(ig) * tanhf(gg);
        float hv = sigmoidf_(og) * tanhf(c);
        out_c1[b * HL + j] = c;
        out_h1[b * HL + j] = hv;
        sh1[j] = hv;
    }
    __syncthreads();

    if (j < OUT) {
        float a = fc_b[j];
#pragma unroll
        for (int k = 0; k < HL; ++k) a = fmaf(sh1[k], fc_w[j * HL + k], a);
        slog[j] = a;
    }
    __syncthreads();

    if (j < OUT) {
        float m = -1e30f;
#pragma unroll
        for (int k = 0; k < OUT; ++k) m = fmaxf(m, slog[k]);
        float s = 0.0f;
#pragma unroll
        for (int k = 0; k < OUT; ++k) s += expf(slog[k] - m);
        out_probs[b * OUT + j] = expf(slog[j] - m) / s;
    }
}

// ---------------------------------------------------------------------------
extern "C" void kernel_launch(void* const* d_in, const int* in_sizes, int n_in,
                              void* d_out, int out_size, void* d_ws, size_t ws_size,
                              hipStream_t stream)
{
    const float* x     = (const float*)d_in[0];
    const int*   ei    = (const int*)  d_in[1];
    const int*   batch = (const int*)  d_in[2];
    const float* w1    = (const float*)d_in[3];
    const float* b1    = (const float*)d_in[4];
    const float* w2    = (const float*)d_in[5];
    const float* b2    = (const float*)d_in[6];
    const float* w3    = (const float*)d_in[7];
    const float* b3    = (const float*)d_in[8];
    const float* w4    = (const float*)d_in[9];
    const float* b4    = (const float*)d_in[10];
    const float* w_ih  = (const float*)d_in[11];
    const float* w_hh  = (const float*)d_in[12];
    const float* b_ih  = (const float*)d_in[13];
    const float* b_hh  = (const float*)d_in[14];
    const float* fc_w  = (const float*)d_in[15];
    const float* fc_b  = (const float*)d_in[16];
    const float* h0    = (const float*)d_in[17];
    const float* c0    = (const float*)d_in[18];

    // workspace layout (~13 MB); xb/h1 have N+16 rows (row ZROW = 0)
    const size_t NR = (size_t)N_NODES + 16;
    int* bincnt = (int*)d_ws;                                 // 256 ints
    unsigned* binbuf = (unsigned*)(bincnt + 256);             // BINS*BCAP
    unsigned short* xb = (unsigned short*)(binbuf + (size_t)BINS * BCAP);
    unsigned short* h1 = xb + NR * D;                         // [NR,64] mlp1 out
    unsigned short* wb = h1 + NR * D;                         // 4 x [64,64] bf16
    float* psum = (float*)(wb + 4 * D * D);                   // [B,64]

    float* out_probs = (float*)d_out;
    float* out_h1    = out_probs + B * OUT;
    float* out_c1    = out_h1 + B * HL;

    // ---- bincnt zero (1 KB) + fused prologue (binA || cvt || init) ----
    hipMemsetAsync(bincnt, 0, 256 * sizeof(int), stream);
    fused_pro_kernel<<<AB + CB + 1, 256, 0, stream>>>(
        ei, bincnt, binbuf, x, xb, w1, w2, w3, w4, wb, h1, psum);

    // ---- layer 1 (fused bucket-build + gather + MLP) ----
    gmlp_kernel<<<MB, 256, 0, stream>>>(xb, bincnt, binbuf,
                                        wb, b1, wb + 4096, b2, h1);

    // ---- layer 2 (fused bucket-build + gather + MLP + pool) ----
    g2mlp_pool_kernel<<<MB, 256, 0, stream>>>(h1, bincnt, binbuf,
                                              wb + 8192, b3, wb + 12288, b4,
                                              batch, psum);

    // ---- head ----
    head_kernel<<<B, 512, 0, stream>>>(psum, batch, w_ih, w_hh, b_ih, b_hh,
                                       fc_w, fc_b, h0, c0,
                                       out_probs, out_h1, out_c1);
}